// Round 2
// baseline (718.621 us; speedup 1.0000x reference)
//
#include <hip/hip_runtime.h>

#define SEQ    256
#define BATCH  32
#define NT     2
#define DIM    128
#define LTAPE  256

typedef float f32x4 __attribute__((ext_vector_type(4)));
typedef short s16x8 __attribute__((ext_vector_type(8)));
typedef unsigned int u32;

__device__ __forceinline__ float sigm(float x) { return 1.f / (1.f + __expf(-x)); }
__device__ __forceinline__ float tanh_(float x) { float e = __expf(2.f * x); return 1.f - 2.f / (e + 1.f); }
__device__ __forceinline__ unsigned short f2bf(float x) {
  u32 u = __builtin_bit_cast(u32, x);
  u32 r = (u + 0x7fffu + ((u >> 16) & 1u)) >> 16;
  return (unsigned short)r;
}
__device__ __forceinline__ float bf2f(unsigned short b) {
  u32 u = ((u32)b) << 16; return __builtin_bit_cast(float, u);
}

// ---------------------------------------------------------------------------
// bf16 MFMA GEMM: C[M][N] = A[M][256] @ W[N][256]^T + bias.  BM=128 BN=64 BK=32.
// 4 waves (2x2), wave tile 64x32 (4x2 frags of 16x16x32).
// ---------------------------------------------------------------------------
template<bool A_BF16, bool OUT_BF16>
__global__ __launch_bounds__(256) void gemm_mfma(
    const void* __restrict__ Av, const float* __restrict__ W,
    const float* __restrict__ bias, void* __restrict__ Cv, int N) {
  __shared__ unsigned short As[128 * 40];
  __shared__ unsigned short Bs[64 * 40];
  const int tid = threadIdx.x;
  const int bm = blockIdx.x * 128, bn = blockIdx.y * 64;
  const int wv = tid >> 6, lane = tid & 63;
  const int wm = wv >> 1, wn = wv & 1;
  const int l15 = lane & 15, l4 = lane >> 4;
  f32x4 acc[4][2] = {};
  const int arow = tid >> 1, ahalf = tid & 1;
  const int brow = (tid & 127) >> 1, bhalf = tid & 1;

  for (int k0 = 0; k0 < 256; k0 += 32) {
    unsigned short abuf[16];
    if (A_BF16) {
      const unsigned short* A = (const unsigned short*)Av;
      const uint4* p = (const uint4*)(A + (size_t)(bm + arow) * 256 + k0 + ahalf * 16);
      *(uint4*)(abuf) = p[0]; *(uint4*)(abuf + 8) = p[1];
    } else {
      const float* A = (const float*)Av;
      const float* src = A + (size_t)(bm + arow) * 256 + k0 + ahalf * 16;
      float4 x0 = ((const float4*)src)[0], x1 = ((const float4*)src)[1];
      float4 x2 = ((const float4*)src)[2], x3 = ((const float4*)src)[3];
      float xs[16] = {x0.x, x0.y, x0.z, x0.w, x1.x, x1.y, x1.z, x1.w,
                      x2.x, x2.y, x2.z, x2.w, x3.x, x3.y, x3.z, x3.w};
#pragma unroll
      for (int j = 0; j < 16; ++j) abuf[j] = f2bf(xs[j]);
    }
    unsigned short bbuf[16];
    if (tid < 128) {
      const float* src = W + (size_t)(bn + brow) * 256 + k0 + bhalf * 16;
      float4 x0 = ((const float4*)src)[0], x1 = ((const float4*)src)[1];
      float4 x2 = ((const float4*)src)[2], x3 = ((const float4*)src)[3];
      float xs[16] = {x0.x, x0.y, x0.z, x0.w, x1.x, x1.y, x1.z, x1.w,
                      x2.x, x2.y, x2.z, x2.w, x3.x, x3.y, x3.z, x3.w};
#pragma unroll
      for (int j = 0; j < 16; ++j) bbuf[j] = f2bf(xs[j]);
    }
    __syncthreads();  // protect previous iteration's ds_reads
    *(uint4*)&As[arow * 40 + ahalf * 16] = *(const uint4*)(abuf);
    *(uint4*)&As[arow * 40 + ahalf * 16 + 8] = *(const uint4*)(abuf + 8);
    if (tid < 128) {
      *(uint4*)&Bs[brow * 40 + bhalf * 16] = *(const uint4*)(bbuf);
      *(uint4*)&Bs[brow * 40 + bhalf * 16 + 8] = *(const uint4*)(bbuf + 8);
    }
    __syncthreads();
    s16x8 af[4], bfr[2];
#pragma unroll
    for (int mi = 0; mi < 4; ++mi)
      af[mi] = *(const s16x8*)&As[(wm * 64 + mi * 16 + l15) * 40 + l4 * 8];
#pragma unroll
    for (int ni = 0; ni < 2; ++ni)
      bfr[ni] = *(const s16x8*)&Bs[(wn * 32 + ni * 16 + l15) * 40 + l4 * 8];
#pragma unroll
    for (int mi = 0; mi < 4; ++mi)
#pragma unroll
      for (int ni = 0; ni < 2; ++ni)
        acc[mi][ni] = __builtin_amdgcn_mfma_f32_16x16x32_bf16(af[mi], bfr[ni], acc[mi][ni], 0, 0, 0);
  }
#pragma unroll
  for (int mi = 0; mi < 4; ++mi)
#pragma unroll
    for (int ni = 0; ni < 2; ++ni)
#pragma unroll
      for (int r = 0; r < 4; ++r) {
        int row = bm + wm * 64 + mi * 16 + l4 * 4 + r;
        int col = bn + wn * 32 + ni * 16 + l15;
        float val = acc[mi][ni][r] + bias[col];
        if (OUT_BF16) ((unsigned short*)Cv)[(size_t)row * N + col] = f2bf(val);
        else          ((float*)Cv)[(size_t)row * N + col] = val;
      }
}

// ---------------------------------------------------------------------------
// f32 SIMT GEMM (kept only for xg, N=64): exact-precision LSTM inputs.
// ---------------------------------------------------------------------------
__global__ __launch_bounds__(256) void gemm_nt(
    const float* __restrict__ A, const float* __restrict__ W,
    const float* __restrict__ b1, const float* __restrict__ b2,
    float* __restrict__ C, int N) {
  __shared__ float Asm[16][68];
  __shared__ float Bsm[16][68];
  const int tid = threadIdx.x;
  const int bm = blockIdx.x * 64;
  const int bn = blockIdx.y * 64;
  const int lr = tid >> 2;
  const int lc4 = (tid & 3) * 4;
  const int tm = (tid & 15) * 4;
  const int tn = (tid >> 4) * 4;
  float acc[4][4];
#pragma unroll
  for (int i = 0; i < 4; ++i)
#pragma unroll
    for (int j = 0; j < 4; ++j) acc[i][j] = 0.f;
  for (int k0 = 0; k0 < 256; k0 += 16) {
    float4 av = *reinterpret_cast<const float4*>(&A[(bm + lr) * 256 + k0 + lc4]);
    float4 bv = *reinterpret_cast<const float4*>(&W[(bn + lr) * 256 + k0 + lc4]);
    __syncthreads();
    Asm[lc4 + 0][lr] = av.x; Asm[lc4 + 1][lr] = av.y; Asm[lc4 + 2][lr] = av.z; Asm[lc4 + 3][lr] = av.w;
    Bsm[lc4 + 0][lr] = bv.x; Bsm[lc4 + 1][lr] = bv.y; Bsm[lc4 + 2][lr] = bv.z; Bsm[lc4 + 3][lr] = bv.w;
    __syncthreads();
#pragma unroll
    for (int kk = 0; kk < 16; ++kk) {
      float4 a = *reinterpret_cast<const float4*>(&Asm[kk][tm]);
      float4 b = *reinterpret_cast<const float4*>(&Bsm[kk][tn]);
      float a_[4] = {a.x, a.y, a.z, a.w};
      float b_[4] = {b.x, b.y, b.z, b.w};
#pragma unroll
      for (int i = 0; i < 4; ++i)
#pragma unroll
        for (int j = 0; j < 4; ++j) acc[i][j] += a_[i] * b_[j];
    }
  }
#pragma unroll
  for (int i = 0; i < 4; ++i)
#pragma unroll
    for (int j = 0; j < 4; ++j) {
      int n = bn + tn + j;
      float bias = b1[n] + (b2 ? b2[n] : 0.f);
      C[(size_t)(bm + tm + i) * N + n] = acc[i][j] + bias;
    }
}

// ---------------------------------------------------------------------------
// LSTM + action heads (unchanged from round 1, verified).
// ---------------------------------------------------------------------------
__global__ __launch_bounds__(64) void lstm_kernel(
    const float* __restrict__ xg, const float* __restrict__ W_hh,
    float* __restrict__ dr, float* __restrict__ dw, float* __restrict__ rw) {
  const int b = blockIdx.x;
  const int lane = threadIdx.x;
  const int k = lane & 15;
  const int q = lane >> 4;
  float wrow[16];
#pragma unroll
  for (int kk = 0; kk < 16; ++kk) wrow[kk] = W_hh[lane * 16 + kk];
  float h = 0.f, c = 0.f;
  const int t = k >> 3, e = k & 7, t8 = t * 8;
  for (int s = 0; s < SEQ; ++s) {
    float g = xg[(size_t)(s * BATCH + b) * 64 + lane];
#pragma unroll
    for (int kk = 0; kk < 16; ++kk) g += wrow[kk] * __shfl(h, kk, 64);
    float gi = __shfl(g, k, 64);
    float gf = __shfl(g, 16 + k, 64);
    float gg = __shfl(g, 32 + k, 64);
    float go = __shfl(g, 48 + k, 64);
    c = sigm(gf) * c + sigm(gi) * tanh_(gg);
    h = sigm(go) * tanh_(c);
    float a0 = __shfl(h, t8 + 0, 64), a1 = __shfl(h, t8 + 1, 64), a2 = __shfl(h, t8 + 2, 64);
    float a3 = __shfl(h, t8 + 3, 64), a4 = __shfl(h, t8 + 4, 64), a5 = __shfl(h, t8 + 5, 64);
    float a6 = __shfl(h, t8 + 6, 64), a7 = __shfl(h, t8 + 7, 64);
    if (q == 0) {
      const int base = (s * BATCH + b) * NT + t;
      if (e < 3) {
        float m = fmaxf(a0, fmaxf(a1, a2));
        float e0 = __expf(a0 - m), e1 = __expf(a1 - m), e2 = __expf(a2 - m);
        float inv = 1.f / (e0 + e1 + e2);
        dr[base * 3 + e] = (e == 0 ? e0 : (e == 1 ? e1 : e2)) * inv;
      } else if (e < 6) {
        float m = fmaxf(a3, fmaxf(a4, a5));
        float e0 = __expf(a3 - m), e1 = __expf(a4 - m), e2 = __expf(a5 - m);
        float inv = 1.f / (e0 + e1 + e2);
        dw[base * 3 + (e - 3)] = (e == 3 ? e0 : (e == 4 ? e1 : e2)) * inv;
      } else {
        rw[base * 2 + (e - 6)] = sigm(e == 6 ? a6 : a7);
      }
    }
  }
}

// ---------------------------------------------------------------------------
// Position precompute: one wave per pair (p = b*2+t). lane owns l = lane*4..+3.
// Stores pre-update wpos (f32) and rpos (bf16) per step; final pos -> d_out.
// ---------------------------------------------------------------------------
__global__ __launch_bounds__(64) void pos_kernel(
    const float* __restrict__ dr, const float* __restrict__ dw,
    float* __restrict__ posW, unsigned short* __restrict__ posR,
    float* __restrict__ out_rpos, float* __restrict__ out_wpos) {
  const int p = blockIdx.x, lane = threadIdx.x;
  float r0 = 0, r1 = 0, r2 = 0, r3 = 0, w0 = 0, w1 = 0, w2 = 0, w3 = 0;
  if (lane == 0) { r0 = 1.f; w0 = 1.f; }
  const float* dp0 = dr + (size_t)p * 3;
  const float* wp0 = dw + (size_t)p * 3;
  float crd0 = dp0[0], crd1 = dp0[1], crd2 = dp0[2];
  float cwd0 = wp0[0], cwd1 = wp0[1], cwd2 = wp0[2];
  for (int s = 0; s < SEQ; ++s) {
    int sn = (s + 1 < SEQ) ? s + 1 : s;
    const float* dp = dr + ((size_t)sn * 64 + p) * 3;
    const float* wp = dw + ((size_t)sn * 64 + p) * 3;
    float nrd0 = dp[0], nrd1 = dp[1], nrd2 = dp[2];
    float nwd0 = wp[0], nwd1 = wp[1], nwd2 = wp[2];
    size_t ob = ((size_t)p * 256 + s) * 256 + lane * 4;
    *(float4*)(posW + ob) = make_float4(w0, w1, w2, w3);
    uint2 rp_pack;
    rp_pack.x = (u32)f2bf(r0) | ((u32)f2bf(r1) << 16);
    rp_pack.y = (u32)f2bf(r2) | ((u32)f2bf(r3) << 16);
    *(uint2*)(posR + ob) = rp_pack;
    float rn  = __shfl(r0, (lane + 1) & 63, 64);   // r at l+1 for i=3
    float rpv = __shfl(r3, (lane + 63) & 63, 64);  // r at l-1 for i=0
    float nw0 = r1 * cwd0 + w0 * cwd1 + rpv * cwd2;
    float nr0 = r1 * crd0 + r0 * crd1 + rpv * crd2;
    float nw1 = r2 * cwd0 + w1 * cwd1 + r0 * cwd2;
    float nr1 = r2 * crd0 + r1 * crd1 + r0 * crd2;
    float nw2 = r3 * cwd0 + w2 * cwd1 + r1 * cwd2;
    float nr2 = r3 * crd0 + r2 * crd1 + r1 * crd2;
    float nw3 = rn * cwd0 + w3 * cwd1 + r2 * cwd2;
    float nr3 = rn * crd0 + r3 * crd1 + r2 * crd2;
    r0 = nr0; r1 = nr1; r2 = nr2; r3 = nr3;
    w0 = nw0; w1 = nw1; w2 = nw2; w3 = nw3;
    crd0 = nrd0; crd1 = nrd1; crd2 = nrd2;
    cwd0 = nwd0; cwd1 = nwd1; cwd2 = nwd2;
  }
  out_rpos[(size_t)(lane * 4 + 0) * 64 + p] = r0;
  out_rpos[(size_t)(lane * 4 + 1) * 64 + p] = r1;
  out_rpos[(size_t)(lane * 4 + 2) * 64 + p] = r2;
  out_rpos[(size_t)(lane * 4 + 3) * 64 + p] = r3;
  out_wpos[(size_t)(lane * 4 + 0) * 64 + p] = w0;
  out_wpos[(size_t)(lane * 4 + 1) * 64 + p] = w1;
  out_wpos[(size_t)(lane * 4 + 2) * 64 + p] = w2;
  out_wpos[(size_t)(lane * 4 + 3) * 64 + p] = w3;
}

// ---------------------------------------------------------------------------
// Tape scan, barrier-free. Block = (pair, channel-quarter) via XCD swizzle.
// Wave: c = cq*32 + wv*8 + (lane>>3), lh = lane&7, rows l in [lh*32, lh*32+32).
// Tape in 32 VGPRs/lane; positions streamed from global, 1-step prefetch;
// l-reduce = shfl_xor 1,2,4 within the 8-lane lh group.
// ---------------------------------------------------------------------------
__global__ __launch_bounds__(256, 1) void tape_kernel(
    const unsigned short* __restrict__ values,  // bf16 [8192][256] flat pb*128+c
    const float* __restrict__ posW,             // f32  [64][256][256]
    const unsigned short* __restrict__ posR,    // bf16 [64][256][256]
    const float* __restrict__ rwp,              // f32  [SEQ*64][2]
    unsigned short* __restrict__ reads,         // bf16 [8192][256]
    float* __restrict__ out_tape) {             // f32  [256][64][128]
  const int B = blockIdx.x;
  const int xcd = B & 7, qq = B >> 3;
  const int p = xcd + 8 * (qq >> 2);   // pair: 4 blocks of a pair share an XCD
  const int cq = qq & 3;
  const int tid = threadIdx.x;
  const int wv = tid >> 6, lane = tid & 63;
  const int c8 = lane >> 3, lh = lane & 7;
  const int c = cq * 32 + wv * 8 + c8;

  const float* Wb = posW + (size_t)p * 256 * 256 + lh * 32;
  const unsigned short* Rb = posR + (size_t)p * 256 * 256 + lh * 32;

  float tp[32];
#pragma unroll
  for (int i = 0; i < 32; ++i) tp[i] = 0.f;

  f32x4 WA[8], WB[8];
  uint4 RA[4], RB[4];
  unsigned short vA, vB;
  float2 rwA, rwB;
  {
    const f32x4* wsrc = (const f32x4*)(Wb);
    const uint4* rsrc = (const uint4*)(Rb);
#pragma unroll
    for (int j = 0; j < 8; ++j) WA[j] = wsrc[j];
#pragma unroll
    for (int j = 0; j < 4; ++j) RA[j] = rsrc[j];
    vA = values[(size_t)p * 128 + c];
    rwA = ((const float2*)rwp)[p];
  }

#define TAPE_STEP(S, WC, RC, VC, RWC, WN, RN, VN, RWN)                          \
  {                                                                             \
    int sn = ((S) + 1 < SEQ) ? (S) + 1 : (S);                                   \
    const f32x4* wsrc = (const f32x4*)(Wb + (size_t)sn * 256);                  \
    const uint4* rsrc = (const uint4*)(Rb + (size_t)sn * 256);                  \
    _Pragma("unroll") for (int j = 0; j < 8; ++j) WN[j] = wsrc[j];              \
    _Pragma("unroll") for (int j = 0; j < 4; ++j) RN[j] = rsrc[j];              \
    VN = values[((size_t)sn * 64 + p) * 128 + c];                               \
    RWN = ((const float2*)rwp)[(size_t)sn * 64 + p];                            \
    float pa0 = 0.f, pa1 = 0.f, pa2 = 0.f, pa3 = 0.f;                           \
    _Pragma("unroll") for (int i = 0; i < 32; ++i) {                            \
      float wl = ((const float*)&WC[i >> 2])[i & 3];                            \
      if ((i & 3) == 0) pa0 += tp[i] * wl;                                      \
      else if ((i & 3) == 1) pa1 += tp[i] * wl;                                 \
      else if ((i & 3) == 2) pa2 += tp[i] * wl;                                 \
      else pa3 += tp[i] * wl;                                                   \
    }                                                                           \
    float pa = (pa0 + pa1) + (pa2 + pa3);                                       \
    pa += __shfl_xor(pa, 1, 64);                                                \
    pa += __shfl_xor(pa, 2, 64);                                                \
    pa += __shfl_xor(pa, 4, 64);                                                \
    float delta = (bf2f(VC) - pa) * RWC.y;                                      \
    float q0 = 0.f, q1 = 0.f, q2 = 0.f, q3 = 0.f;                               \
    _Pragma("unroll") for (int i = 0; i < 32; ++i) {                            \
      float wl = ((const float*)&WC[i >> 2])[i & 3];                            \
      u32 word = ((const u32*)&RC[i >> 3])[(i >> 1) & 3];                       \
      float rl = __builtin_bit_cast(float,                                      \
                   (i & 1) ? (word & 0xffff0000u) : (word << 16));              \
      tp[i] += wl * delta;                                                      \
      if ((i & 3) == 0) q0 += tp[i] * rl;                                       \
      else if ((i & 3) == 1) q1 += tp[i] * rl;                                  \
      else if ((i & 3) == 2) q2 += tp[i] * rl;                                  \
      else q3 += tp[i] * rl;                                                    \
    }                                                                           \
    float qs = (q0 + q1) + (q2 + q3);                                           \
    qs += __shfl_xor(qs, 1, 64);                                                \
    qs += __shfl_xor(qs, 2, 64);                                                \
    qs += __shfl_xor(qs, 4, 64);                                                \
    if (lh == 0) reads[((size_t)(S) * 64 + p) * 128 + c] = f2bf(qs * RWC.x);    \
  }

  for (int s = 0; s < SEQ; s += 2) {
    TAPE_STEP(s, WA, RA, vA, rwA, WB, RB, vB, rwB);
    TAPE_STEP(s + 1, WB, RB, vB, rwB, WA, RA, vA, rwA);
  }
#undef TAPE_STEP

#pragma unroll
  for (int i = 0; i < 32; ++i) {
    const int l = lh * 32 + i;
    out_tape[((size_t)l * 64 + p) * 128 + c] = tp[i];
  }
}

// ---------------------------------------------------------------------------
extern "C" void kernel_launch(void* const* d_in, const int* in_sizes, int n_in,
                              void* d_out, int out_size, void* d_ws, size_t ws_size,
                              hipStream_t stream) {
  const float* inputs = (const float*)d_in[0];
  const float* W_ih = (const float*)d_in[2];
  const float* W_hh = (const float*)d_in[3];
  const float* b_ih = (const float*)d_in[4];
  const float* b_hh = (const float*)d_in[5];
  const float* W_val = (const float*)d_in[6];
  const float* b_val = (const float*)d_in[7];
  const float* W_out = (const float*)d_in[8];
  const float* b_out = (const float*)d_in[9];

  float* out = (float*)d_out;
  float* out_tape = out + 2097152;
  float* out_rpos = out + 4194304;
  float* out_wpos = out + 4210688;

  char* ws = (char*)d_ws;
  unsigned short* values_bf = (unsigned short*)(ws);                 //  4,194,304 B
  unsigned short* reads_bf  = (unsigned short*)(ws + 4194304);       //  4,194,304 B
  float* xg   = (float*)(ws + 8388608);                              //  2,097,152 B
  float* drr  = (float*)(ws + 10485760);                             //    196,608 B
  float* dww  = (float*)(ws + 10682368);                             //    196,608 B
  float* rwp  = (float*)(ws + 10878976);                             //    131,072 B
  float* posW = (float*)(ws + 11010048);                             // 16,777,216 B
  unsigned short* posR = (unsigned short*)(ws + 27787264);           //  8,388,608 B  (total ~36.2 MB)

  // values (bf16 out) = inputs @ W_val^T + b_val
  gemm_mfma<false, true><<<dim3(64, 4), 256, 0, stream>>>(inputs, W_val, b_val, values_bf, 256);
  // xg (f32, exact path) = inputs @ W_ih^T + (b_ih + b_hh)
  gemm_nt<<<dim3(128, 1), 256, 0, stream>>>(inputs, W_ih, b_ih, b_hh, xg, 64);
  // LSTM -> direction/probability coefficients
  lstm_kernel<<<32, 64, 0, stream>>>(xg, W_hh, drr, dww, rwp);
  // position trajectories (+ final rpos/wpos outputs)
  pos_kernel<<<64, 64, 0, stream>>>(drr, dww, posW, posR, out_rpos, out_wpos);
  // tape scan -> reads (bf16), final tape
  tape_kernel<<<256, 256, 0, stream>>>(values_bf, posW, posR, rwp, reads_bf, out_tape);
  // outputs = reads @ W_out^T + b_out
  gemm_mfma<true, false><<<dim3(64, 4), 256, 0, stream>>>(reads_bf, W_out, b_out, out, 256);
}

// Round 4
// 561.381 us; speedup vs baseline: 1.2801x; 1.2801x over previous
//
#include <hip/hip_runtime.h>

#define SEQ    256
#define BATCH  32
#define NT     2
#define DIM    128
#define LTAPE  256

typedef float f32x4 __attribute__((ext_vector_type(4)));
typedef short s16x8 __attribute__((ext_vector_type(8)));
typedef unsigned int u32;
typedef unsigned short u16;

__device__ __forceinline__ float sigm(float x) { return 1.f / (1.f + __expf(-x)); }
__device__ __forceinline__ float tanh_(float x) { float e = __expf(2.f * x); return 1.f - 2.f / (e + 1.f); }
__device__ __forceinline__ u16 f2bf(float x) {
  u32 u = __builtin_bit_cast(u32, x);
  u32 r = (u + 0x7fffu + ((u >> 16) & 1u)) >> 16;
  return (u16)r;
}
__device__ __forceinline__ float bf2f(u16 b) {
  u32 u = ((u32)b) << 16; return __builtin_bit_cast(float, u);
}

// ---------------------------------------------------------------------------
// bf16 MFMA GEMM (verified round 2): C[M][N] = A[M][256] @ W[N][256]^T + bias.
// BM=128 BN=64 BK=32, 4 waves (2x2), wave 64x32.
// ---------------------------------------------------------------------------
template<bool A_BF16, bool OUT_BF16>
__global__ __launch_bounds__(256) void gemm_mfma(
    const void* __restrict__ Av, const float* __restrict__ W,
    const float* __restrict__ bias, void* __restrict__ Cv, int N) {
  __shared__ u16 As[128 * 40];
  __shared__ u16 Bs[64 * 40];
  const int tid = threadIdx.x;
  const int bm = blockIdx.x * 128, bn = blockIdx.y * 64;
  const int wv = tid >> 6, lane = tid & 63;
  const int wm = wv >> 1, wn = wv & 1;
  const int l15 = lane & 15, l4 = lane >> 4;
  f32x4 acc[4][2] = {};
  const int arow = tid >> 1, ahalf = tid & 1;
  const int brow = (tid & 127) >> 1, bhalf = tid & 1;

  for (int k0 = 0; k0 < 256; k0 += 32) {
    u16 abuf[16];
    if (A_BF16) {
      const u16* A = (const u16*)Av;
      const uint4* p = (const uint4*)(A + (size_t)(bm + arow) * 256 + k0 + ahalf * 16);
      *(uint4*)(abuf) = p[0]; *(uint4*)(abuf + 8) = p[1];
    } else {
      const float* A = (const float*)Av;
      const float* src = A + (size_t)(bm + arow) * 256 + k0 + ahalf * 16;
      float4 x0 = ((const float4*)src)[0], x1 = ((const float4*)src)[1];
      float4 x2 = ((const float4*)src)[2], x3 = ((const float4*)src)[3];
      float xs[16] = {x0.x, x0.y, x0.z, x0.w, x1.x, x1.y, x1.z, x1.w,
                      x2.x, x2.y, x2.z, x2.w, x3.x, x3.y, x3.z, x3.w};
#pragma unroll
      for (int j = 0; j < 16; ++j) abuf[j] = f2bf(xs[j]);
    }
    u16 bbuf[16];
    if (tid < 128) {
      const float* src = W + (size_t)(bn + brow) * 256 + k0 + bhalf * 16;
      float4 x0 = ((const float4*)src)[0], x1 = ((const float4*)src)[1];
      float4 x2 = ((const float4*)src)[2], x3 = ((const float4*)src)[3];
      float xs[16] = {x0.x, x0.y, x0.z, x0.w, x1.x, x1.y, x1.z, x1.w,
                      x2.x, x2.y, x2.z, x2.w, x3.x, x3.y, x3.z, x3.w};
#pragma unroll
      for (int j = 0; j < 16; ++j) bbuf[j] = f2bf(xs[j]);
    }
    __syncthreads();
    *(uint4*)&As[arow * 40 + ahalf * 16] = *(const uint4*)(abuf);
    *(uint4*)&As[arow * 40 + ahalf * 16 + 8] = *(const uint4*)(abuf + 8);
    if (tid < 128) {
      *(uint4*)&Bs[brow * 40 + bhalf * 16] = *(const uint4*)(bbuf);
      *(uint4*)&Bs[brow * 40 + bhalf * 16 + 8] = *(const uint4*)(bbuf + 8);
    }
    __syncthreads();
    s16x8 af[4], bfr[2];
#pragma unroll
    for (int mi = 0; mi < 4; ++mi)
      af[mi] = *(const s16x8*)&As[(wm * 64 + mi * 16 + l15) * 40 + l4 * 8];
#pragma unroll
    for (int ni = 0; ni < 2; ++ni)
      bfr[ni] = *(const s16x8*)&Bs[(wn * 32 + ni * 16 + l15) * 40 + l4 * 8];
#pragma unroll
    for (int mi = 0; mi < 4; ++mi)
#pragma unroll
      for (int ni = 0; ni < 2; ++ni)
        acc[mi][ni] = __builtin_amdgcn_mfma_f32_16x16x32_bf16(af[mi], bfr[ni], acc[mi][ni], 0, 0, 0);
  }
#pragma unroll
  for (int mi = 0; mi < 4; ++mi)
#pragma unroll
    for (int ni = 0; ni < 2; ++ni)
#pragma unroll
      for (int r = 0; r < 4; ++r) {
        int row = bm + wm * 64 + mi * 16 + l4 * 4 + r;
        int col = bn + wn * 32 + ni * 16 + l15;
        float val = acc[mi][ni][r] + bias[col];
        if (OUT_BF16) ((u16*)Cv)[(size_t)row * N + col] = f2bf(val);
        else          ((float*)Cv)[(size_t)row * N + col] = val;
      }
}

// ---------------------------------------------------------------------------
// f32 SIMT GEMM (xg only, exact path for the LSTM recurrence).
// ---------------------------------------------------------------------------
__global__ __launch_bounds__(256) void gemm_nt(
    const float* __restrict__ A, const float* __restrict__ W,
    const float* __restrict__ b1, const float* __restrict__ b2,
    float* __restrict__ C, int N) {
  __shared__ float Asm[16][68];
  __shared__ float Bsm[16][68];
  const int tid = threadIdx.x;
  const int bm = blockIdx.x * 64;
  const int bn = blockIdx.y * 64;
  const int lr = tid >> 2;
  const int lc4 = (tid & 3) * 4;
  const int tm = (tid & 15) * 4;
  const int tn = (tid >> 4) * 4;
  float acc[4][4];
#pragma unroll
  for (int i = 0; i < 4; ++i)
#pragma unroll
    for (int j = 0; j < 4; ++j) acc[i][j] = 0.f;
  for (int k0 = 0; k0 < 256; k0 += 16) {
    float4 av = *reinterpret_cast<const float4*>(&A[(bm + lr) * 256 + k0 + lc4]);
    float4 bv = *reinterpret_cast<const float4*>(&W[(bn + lr) * 256 + k0 + lc4]);
    __syncthreads();
    Asm[lc4 + 0][lr] = av.x; Asm[lc4 + 1][lr] = av.y; Asm[lc4 + 2][lr] = av.z; Asm[lc4 + 3][lr] = av.w;
    Bsm[lc4 + 0][lr] = bv.x; Bsm[lc4 + 1][lr] = bv.y; Bsm[lc4 + 2][lr] = bv.z; Bsm[lc4 + 3][lr] = bv.w;
    __syncthreads();
#pragma unroll
    for (int kk = 0; kk < 16; ++kk) {
      float4 a = *reinterpret_cast<const float4*>(&Asm[kk][tm]);
      float4 b = *reinterpret_cast<const float4*>(&Bsm[kk][tn]);
      float a_[4] = {a.x, a.y, a.z, a.w};
      float b_[4] = {b.x, b.y, b.z, b.w};
#pragma unroll
      for (int i = 0; i < 4; ++i)
#pragma unroll
        for (int j = 0; j < 4; ++j) acc[i][j] += a_[i] * b_[j];
    }
  }
#pragma unroll
  for (int i = 0; i < 4; ++i)
#pragma unroll
    for (int j = 0; j < 4; ++j) {
      int n = bn + tn + j;
      float bias = b1[n] + (b2 ? b2[n] : 0.f);
      C[(size_t)(bm + tm + i) * N + n] = acc[i][j] + bias;
    }
}

// ---------------------------------------------------------------------------
// LSTM + action heads (verified rounds 1-2).
// ---------------------------------------------------------------------------
__global__ __launch_bounds__(64) void lstm_kernel(
    const float* __restrict__ xg, const float* __restrict__ W_hh,
    float* __restrict__ dr, float* __restrict__ dw, float* __restrict__ rw) {
  const int b = blockIdx.x;
  const int lane = threadIdx.x;
  const int k = lane & 15;
  const int q = lane >> 4;
  float wrow[16];
#pragma unroll
  for (int kk = 0; kk < 16; ++kk) wrow[kk] = W_hh[lane * 16 + kk];
  float h = 0.f, c = 0.f;
  const int t = k >> 3, e = k & 7, t8 = t * 8;
  for (int s = 0; s < SEQ; ++s) {
    float g = xg[(size_t)(s * BATCH + b) * 64 + lane];
#pragma unroll
    for (int kk = 0; kk < 16; ++kk) g += wrow[kk] * __shfl(h, kk, 64);
    float gi = __shfl(g, k, 64);
    float gf = __shfl(g, 16 + k, 64);
    float gg = __shfl(g, 32 + k, 64);
    float go = __shfl(g, 48 + k, 64);
    c = sigm(gf) * c + sigm(gi) * tanh_(gg);
    h = sigm(go) * tanh_(c);
    float a0 = __shfl(h, t8 + 0, 64), a1 = __shfl(h, t8 + 1, 64), a2 = __shfl(h, t8 + 2, 64);
    float a3 = __shfl(h, t8 + 3, 64), a4 = __shfl(h, t8 + 4, 64), a5 = __shfl(h, t8 + 5, 64);
    float a6 = __shfl(h, t8 + 6, 64), a7 = __shfl(h, t8 + 7, 64);
    if (q == 0) {
      const int base = (s * BATCH + b) * NT + t;
      if (e < 3) {
        float m = fmaxf(a0, fmaxf(a1, a2));
        float e0 = __expf(a0 - m), e1 = __expf(a1 - m), e2 = __expf(a2 - m);
        float inv = 1.f / (e0 + e1 + e2);
        dr[base * 3 + e] = (e == 0 ? e0 : (e == 1 ? e1 : e2)) * inv;
      } else if (e < 6) {
        float m = fmaxf(a3, fmaxf(a4, a5));
        float e0 = __expf(a3 - m), e1 = __expf(a4 - m), e2 = __expf(a5 - m);
        float inv = 1.f / (e0 + e1 + e2);
        dw[base * 3 + (e - 3)] = (e == 3 ? e0 : (e == 4 ? e1 : e2)) * inv;
      } else {
        rw[base * 2 + (e - 6)] = sigm(e == 6 ? a6 : a7);
      }
    }
  }
}

// ---------------------------------------------------------------------------
// Position precompute (recurrence verified round 2). Stores per-step
// pre-update wpos (f32) and rw0-scaled rpos (f32); final pos -> d_out.
// ---------------------------------------------------------------------------
__global__ __launch_bounds__(64) void pos_kernel(
    const float* __restrict__ dr, const float* __restrict__ dw,
    const float* __restrict__ rwp,
    float* __restrict__ posW, float* __restrict__ posRs,
    float* __restrict__ out_rpos, float* __restrict__ out_wpos) {
  const int p = blockIdx.x, lane = threadIdx.x;
  float r0 = 0, r1 = 0, r2 = 0, r3 = 0, w0 = 0, w1 = 0, w2 = 0, w3 = 0;
  if (lane == 0) { r0 = 1.f; w0 = 1.f; }
  const float* dp0 = dr + (size_t)p * 3;
  const float* wp0 = dw + (size_t)p * 3;
  float crd0 = dp0[0], crd1 = dp0[1], crd2 = dp0[2];
  float cwd0 = wp0[0], cwd1 = wp0[1], cwd2 = wp0[2];
  for (int s = 0; s < SEQ; ++s) {
    int sn = (s + 1 < SEQ) ? s + 1 : s;
    const float* dp = dr + ((size_t)sn * 64 + p) * 3;
    const float* wp = dw + ((size_t)sn * 64 + p) * 3;
    float nrd0 = dp[0], nrd1 = dp[1], nrd2 = dp[2];
    float nwd0 = wp[0], nwd1 = wp[1], nwd2 = wp[2];
    float rw0 = rwp[((size_t)s * 64 + p) * 2 + 0];
    size_t ob = ((size_t)p * 256 + s) * 256 + lane * 4;
    *(float4*)(posW + ob) = make_float4(w0, w1, w2, w3);
    *(float4*)(posRs + ob) = make_float4(r0 * rw0, r1 * rw0, r2 * rw0, r3 * rw0);
    float rn  = __shfl(r0, (lane + 1) & 63, 64);
    float rpv = __shfl(r3, (lane + 63) & 63, 64);
    float nw0 = r1 * cwd0 + w0 * cwd1 + rpv * cwd2;
    float nr0 = r1 * crd0 + r0 * crd1 + rpv * crd2;
    float nw1 = r2 * cwd0 + w1 * cwd1 + r0 * cwd2;
    float nr1 = r2 * crd0 + r1 * crd1 + r0 * crd2;
    float nw2 = r3 * cwd0 + w2 * cwd1 + r1 * cwd2;
    float nr2 = r3 * crd0 + r2 * crd1 + r1 * crd2;
    float nw3 = rn * cwd0 + w3 * cwd1 + r2 * cwd2;
    float nr3 = rn * crd0 + r3 * crd1 + r2 * crd2;
    r0 = nr0; r1 = nr1; r2 = nr2; r3 = nr3;
    w0 = nw0; w1 = nw1; w2 = nw2; w3 = nw3;
    crd0 = nrd0; crd1 = nrd1; crd2 = nrd2;
    cwd0 = nwd0; cwd1 = nwd1; cwd2 = nwd2;
  }
  out_rpos[(size_t)(lane * 4 + 0) * 64 + p] = r0;
  out_rpos[(size_t)(lane * 4 + 1) * 64 + p] = r1;
  out_rpos[(size_t)(lane * 4 + 2) * 64 + p] = r2;
  out_rpos[(size_t)(lane * 4 + 3) * 64 + p] = r3;
  out_wpos[(size_t)(lane * 4 + 0) * 64 + p] = w0;
  out_wpos[(size_t)(lane * 4 + 1) * 64 + p] = w1;
  out_wpos[(size_t)(lane * 4 + 2) * 64 + p] = w2;
  out_wpos[(size_t)(lane * 4 + 3) * 64 + p] = w3;
}

// ---------------------------------------------------------------------------
// Batched per-pair GEMM with hi/lo bf16 compensation (3 MFMA terms ~ f32).
// C[p][M=256][N] = A·B. TRANS_A: A is [K][M] else [M][K] (row len 256).
// B_NT: B is [N][K] (row len 256) else [K][N] (row len BROW).
// MODE: 0 plain, 1 strict-lower x rw1[row], 2 lower-incl.
// OUTK: 0 C+p*65536+row*256+col ; 1 reads layout ; 2 tape layout.
// Block tile 128x64, 4 waves (2x2), wave 64x32, BK=32.
// ---------------------------------------------------------------------------
template<bool TRANS_A, bool B_NT, int MODE, int OUTK, int BROW>
__global__ __launch_bounds__(256) void bgemm(
    const float* __restrict__ A, const float* __restrict__ B,
    const float* __restrict__ rwp, float* __restrict__ C,
    size_t sA, size_t sB) {
  __shared__ u16 Ah[128 * 40], Al[128 * 40], Bh[64 * 40], Bl[64 * 40];
  const int p = blockIdx.z;
  const int bm = blockIdx.y * 128, bn = blockIdx.x * 64;
  const int tid = threadIdx.x, wv = tid >> 6, lane = tid & 63;
  const int wm = wv >> 1, wn = wv & 1, l15 = lane & 15, l4 = lane >> 4;
  const float* Ap = A + (size_t)p * sA;
  const float* Bp = B + (size_t)p * sB;
  f32x4 acc[4][2] = {};

  for (int k0 = 0; k0 < 256; k0 += 32) {
    // ---- load + split A tile ----
    float xa[16];
    if (!TRANS_A) {
      const int m = tid >> 1, kq = (tid & 1) * 16;
      const float* src = Ap + (size_t)(bm + m) * 256 + k0 + kq;
#pragma unroll
      for (int j = 0; j < 4; ++j) *(float4*)(xa + j * 4) = ((const float4*)src)[j];
    } else {
      const int kr = tid >> 3, mq = (tid & 7) * 16;
      const float* src = Ap + (size_t)(k0 + kr) * 256 + bm + mq;
#pragma unroll
      for (int j = 0; j < 4; ++j) *(float4*)(xa + j * 4) = ((const float4*)src)[j];
    }
    u16 ah[16], al[16];
#pragma unroll
    for (int j = 0; j < 16; ++j) {
      u16 hh = f2bf(xa[j]);
      ah[j] = hh; al[j] = f2bf(xa[j] - bf2f(hh));
    }
    // ---- load + split B tile ----
    float xb[8];
    if (B_NT) {
      const int n = tid >> 2, kq = (tid & 3) * 8;
      const float* src = Bp + (size_t)(bn + n) * 256 + k0 + kq;
      *(float4*)(xb) = ((const float4*)src)[0];
      *(float4*)(xb + 4) = ((const float4*)src)[1];
    } else {
      const int kr = tid >> 3, nq = (tid & 7) * 8;
      const float* src = Bp + (size_t)(k0 + kr) * BROW + bn + nq;
      *(float4*)(xb) = ((const float4*)src)[0];
      *(float4*)(xb + 4) = ((const float4*)src)[1];
    }
    u16 bh[8], bl[8];
#pragma unroll
    for (int j = 0; j < 8; ++j) {
      u16 hh = f2bf(xb[j]);
      bh[j] = hh; bl[j] = f2bf(xb[j] - bf2f(hh));
    }
    __syncthreads();  // protect previous iteration's fragment reads
    // ---- store LDS ----
    if (!TRANS_A) {
      const int m = tid >> 1, kq = (tid & 1) * 16;
      *(uint4*)&Ah[m * 40 + kq]     = *(const uint4*)(ah);
      *(uint4*)&Ah[m * 40 + kq + 8] = *(const uint4*)(ah + 8);
      *(uint4*)&Al[m * 40 + kq]     = *(const uint4*)(al);
      *(uint4*)&Al[m * 40 + kq + 8] = *(const uint4*)(al + 8);
    } else {
      const int kr = tid >> 3, mq = (tid & 7) * 16;
#pragma unroll
      for (int j = 0; j < 16; ++j) {
        Ah[(mq + j) * 40 + kr] = ah[j];
        Al[(mq + j) * 40 + kr] = al[j];
      }
    }
    if (B_NT) {
      const int n = tid >> 2, kq = (tid & 3) * 8;
      *(uint4*)&Bh[n * 40 + kq] = *(const uint4*)(bh);
      *(uint4*)&Bl[n * 40 + kq] = *(const uint4*)(bl);
    } else {
      const int kr = tid >> 3, nq = (tid & 7) * 8;
#pragma unroll
      for (int j = 0; j < 8; ++j) {
        Bh[(nq + j) * 40 + kr] = bh[j];
        Bl[(nq + j) * 40 + kr] = bl[j];
      }
    }
    __syncthreads();
    // ---- MFMA: acc += Ah*Bh + Ah*Bl + Al*Bh ----
    s16x8 fah[4], fal[4], fbh[2], fbl[2];
#pragma unroll
    for (int mi = 0; mi < 4; ++mi) {
      fah[mi] = *(const s16x8*)&Ah[(wm * 64 + mi * 16 + l15) * 40 + l4 * 8];
      fal[mi] = *(const s16x8*)&Al[(wm * 64 + mi * 16 + l15) * 40 + l4 * 8];
    }
#pragma unroll
    for (int ni = 0; ni < 2; ++ni) {
      fbh[ni] = *(const s16x8*)&Bh[(wn * 32 + ni * 16 + l15) * 40 + l4 * 8];
      fbl[ni] = *(const s16x8*)&Bl[(wn * 32 + ni * 16 + l15) * 40 + l4 * 8];
    }
#pragma unroll
    for (int mi = 0; mi < 4; ++mi)
#pragma unroll
      for (int ni = 0; ni < 2; ++ni) {
        acc[mi][ni] = __builtin_amdgcn_mfma_f32_16x16x32_bf16(fah[mi], fbh[ni], acc[mi][ni], 0, 0, 0);
        acc[mi][ni] = __builtin_amdgcn_mfma_f32_16x16x32_bf16(fah[mi], fbl[ni], acc[mi][ni], 0, 0, 0);
        acc[mi][ni] = __builtin_amdgcn_mfma_f32_16x16x32_bf16(fal[mi], fbh[ni], acc[mi][ni], 0, 0, 0);
      }
  }
  // ---- epilogue ----
  const int b = p >> 1, t = p & 1;
#pragma unroll
  for (int mi = 0; mi < 4; ++mi)
#pragma unroll
    for (int ni = 0; ni < 2; ++ni)
#pragma unroll
      for (int r = 0; r < 4; ++r) {
        int row = bm + wm * 64 + mi * 16 + l4 * 4 + r;
        int col = bn + wn * 32 + ni * 16 + l15;
        float v = acc[mi][ni][r];
        if (MODE == 1) v = (col < row) ? v * rwp[((size_t)row * 64 + p) * 2 + 1] : 0.f;
        if (MODE == 2) v = (col <= row) ? v : 0.f;
        if (OUTK == 0)      C[(size_t)p * 65536 + (size_t)row * 256 + col] = v;
        else if (OUTK == 1) C[((size_t)(row * 32 + b)) * 256 + t * 128 + col] = v;
        else                C[((size_t)row * 64 + p) * 128 + col] = v;
      }
}

// ---------------------------------------------------------------------------
// Blocked triangular solve (I + L) delta = rw1 * v.  Grid 128 = (pair, chalf).
// 4 waves: wave w computes off-diag partials for rows w*8..w*8+7 of the
// current 32-row block; wave 0 then does the sequential 32-row solve.
// ---------------------------------------------------------------------------
__global__ __launch_bounds__(256) void solve_kernel(
    const float* __restrict__ L,        // [64][256][256] strict-lower, rw1-scaled
    const u16* __restrict__ values,     // bf16 [8192][256]
    const float* __restrict__ rwp,      // [(s*64+p)][2]
    float* __restrict__ delta) {        // [64][256][128]
  const int p = blockIdx.x >> 1, half = blockIdx.x & 1;
  const int b = p >> 1, t = p & 1;
  const int tid = threadIdx.x, w = tid >> 6, lane = tid & 63;
  __shared__ float ds[256][64];
  __shared__ float Ps[32][64];
  __shared__ float Db[32][33];
  const float* Lp = L + (size_t)p * 65536;

  for (int k = 0; k < 8; ++k) {
    const int s0 = k * 32;
    // b = rw1 * v for this wave's 8 rows
    float acc[8];
#pragma unroll
    for (int i = 0; i < 8; ++i) {
      const int s = s0 + w * 8 + i;
      float rv = bf2f(values[((size_t)(s * 32 + b)) * 256 + t * 128 + half * 64 + lane]);
      acc[i] = rv * rwp[((size_t)s * 64 + p) * 2 + 1];
    }
    // off-diagonal: acc[i] -= sum_{j<s0} L[s][j] * delta[j]
    const float* Lr0 = Lp + (size_t)(s0 + w * 8) * 256;
#pragma unroll 4
    for (int j = 0; j < s0; ++j) {
      float dj = ds[j][lane];
#pragma unroll
      for (int i = 0; i < 8; ++i) acc[i] -= Lr0[(size_t)i * 256 + j] * dj;
    }
    // stage diagonal 32x32 tile
    {
      const int r = tid >> 3, q0 = (tid & 7) * 4;
      float4 dv = *(const float4*)(Lp + (size_t)(s0 + r) * 256 + s0 + q0);
      Db[r][q0] = dv.x; Db[r][q0 + 1] = dv.y; Db[r][q0 + 2] = dv.z; Db[r][q0 + 3] = dv.w;
    }
#pragma unroll
    for (int i = 0; i < 8; ++i) Ps[w * 8 + i][lane] = acc[i];
    __syncthreads();
    if (w == 0) {
      float d[32];
#pragma unroll
      for (int r = 0; r < 32; ++r) {
        float xa = Ps[r][lane], xb = 0.f;
#pragma unroll
        for (int q = 0; q < 32; ++q) {
          if (q < r) {
            if (q & 1) xb -= Db[r][q] * d[q];
            else       xa -= Db[r][q] * d[q];
          }
        }
        float x = xa + xb;
        d[r] = x;
        ds[s0 + r][lane] = x;
        delta[((size_t)p * 256 + s0 + r) * 128 + half * 64 + lane] = x;
      }
    }
    __syncthreads();
  }
}

// ---------------------------------------------------------------------------
extern "C" void kernel_launch(void* const* d_in, const int* in_sizes, int n_in,
                              void* d_out, int out_size, void* d_ws, size_t ws_size,
                              hipStream_t stream) {
  const float* inputs = (const float*)d_in[0];
  const float* W_ih = (const float*)d_in[2];
  const float* W_hh = (const float*)d_in[3];
  const float* b_ih = (const float*)d_in[4];
  const float* b_hh = (const float*)d_in[5];
  const float* W_val = (const float*)d_in[6];
  const float* b_val = (const float*)d_in[7];
  const float* W_out = (const float*)d_in[8];
  const float* b_out = (const float*)d_in[9];

  float* out = (float*)d_out;
  float* out_tape = out + 2097152;
  float* out_rpos = out + 4194304;
  float* out_wpos = out + 4210688;

  char* ws = (char*)d_ws;
  float* posW      = (float*)(ws);                    // 16 MB  [64][256][256]
  float* posRs     = (float*)(ws + 16777216);         // 16 MB  (later: reads_f32 8MB)
  float* LHm       = (float*)(ws + 33554432);         // 16 MB  (L, then Hm)
  u16*   values_bf = (u16*)  (ws + 50331648);         //  4 MB
  float* xg        = (float*)(ws + 54525952);         //  2 MB (dead after lstm)
  float* delta     = (float*)(ws + 54525952);         //  8 MB (aliases xg)
  float* drr       = (float*)(ws + 62914560);         // 192 KB
  float* dww       = (float*)(ws + 63111168);         // 192 KB
  float* rwp       = (float*)(ws + 63307776);         // 128 KB  (end ~63.4 MB)
  float* reads_f32 = posRs;                           // reuse after H

  // 1. values (bf16) = inputs @ W_val^T + b_val
  gemm_mfma<false, true><<<dim3(64, 4), 256, 0, stream>>>(inputs, W_val, b_val, values_bf, 256);
  // 2. xg (f32) = inputs @ W_ih^T + (b_ih + b_hh)
  gemm_nt<<<dim3(128, 1), 256, 0, stream>>>(inputs, W_ih, b_ih, b_hh, xg, 64);
  // 3. LSTM -> dirs / rw probs
  lstm_kernel<<<32, 64, 0, stream>>>(xg, W_hh, drr, dww, rwp);
  // 4. position trajectories
  pos_kernel<<<64, 64, 0, stream>>>(drr, dww, rwp, posW, posRs, out_rpos, out_wpos);
  // 5. L = rw1 (.) strict_tril(posW posW^T)
  bgemm<false, true, 1, 0, 256><<<dim3(4, 2, 64), 256, 0, stream>>>(
      posW, posW, rwp, LHm, 65536, 65536);
  // 6. blocked triangular solve -> delta
  solve_kernel<<<128, 256, 0, stream>>>(LHm, values_bf, rwp, delta);
  // 7. Hm = tril_incl(posRs posW^T)   (overwrites L)
  bgemm<false, true, 2, 0, 256><<<dim3(4, 2, 64), 256, 0, stream>>>(
      posRs, posW, nullptr, LHm, 65536, 65536);
  // 8. reads = Hm @ delta   (into posRs buffer, reads layout [s*32+b][256])
  bgemm<false, false, 0, 1, 128><<<dim3(2, 2, 64), 256, 0, stream>>>(
      LHm, delta, nullptr, reads_f32, 65536, 32768);
  // 9. out_tape = posW^T @ delta
  bgemm<true, false, 0, 2, 128><<<dim3(2, 2, 64), 256, 0, stream>>>(
      posW, delta, nullptr, out_tape, 65536, 32768);
  // 10. outputs = reads @ W_out^T + b_out
  gemm_mfma<false, false><<<dim3(64, 4), 256, 0, stream>>>(reads_f32, W_out, b_out, out, 256);
}

// Round 5
// 522.827 us; speedup vs baseline: 1.3745x; 1.0737x over previous
//
#include <hip/hip_runtime.h>

#define SEQ    256
#define BATCH  32
#define NT     2
#define DIM    128
#define LTAPE  256

typedef float f32x4 __attribute__((ext_vector_type(4)));
typedef short s16x8 __attribute__((ext_vector_type(8)));
typedef unsigned int u32;
typedef unsigned short u16;

__device__ __forceinline__ float sigm(float x) { return 1.f / (1.f + __expf(-x)); }
__device__ __forceinline__ float tanh_(float x) { float e = __expf(2.f * x); return 1.f - 2.f / (e + 1.f); }
__device__ __forceinline__ u16 f2bf(float x) {
  u32 u = __builtin_bit_cast(u32, x);
  u32 r = (u + 0x7fffu + ((u >> 16) & 1u)) >> 16;
  return (u16)r;
}
__device__ __forceinline__ float bf2f(u16 b) {
  u32 u = ((u32)b) << 16; return __builtin_bit_cast(float, u);
}

// ---------------------------------------------------------------------------
// bf16 MFMA GEMM (verified): C[M][N] = A[M][256] @ W[N][256]^T + bias.
// ---------------------------------------------------------------------------
template<bool A_BF16, bool OUT_BF16>
__global__ __launch_bounds__(256) void gemm_mfma(
    const void* __restrict__ Av, const float* __restrict__ W,
    const float* __restrict__ bias, void* __restrict__ Cv, int N) {
  __shared__ u16 As[128 * 40];
  __shared__ u16 Bs[64 * 40];
  const int tid = threadIdx.x;
  const int bm = blockIdx.x * 128, bn = blockIdx.y * 64;
  const int wv = tid >> 6, lane = tid & 63;
  const int wm = wv >> 1, wn = wv & 1;
  const int l15 = lane & 15, l4 = lane >> 4;
  f32x4 acc[4][2] = {};
  const int arow = tid >> 1, ahalf = tid & 1;
  const int brow = (tid & 127) >> 1, bhalf = tid & 1;

  for (int k0 = 0; k0 < 256; k0 += 32) {
    u16 abuf[16];
    if (A_BF16) {
      const u16* A = (const u16*)Av;
      const uint4* p = (const uint4*)(A + (size_t)(bm + arow) * 256 + k0 + ahalf * 16);
      *(uint4*)(abuf) = p[0]; *(uint4*)(abuf + 8) = p[1];
    } else {
      const float* A = (const float*)Av;
      const float* src = A + (size_t)(bm + arow) * 256 + k0 + ahalf * 16;
      float4 x0 = ((const float4*)src)[0], x1 = ((const float4*)src)[1];
      float4 x2 = ((const float4*)src)[2], x3 = ((const float4*)src)[3];
      float xs[16] = {x0.x, x0.y, x0.z, x0.w, x1.x, x1.y, x1.z, x1.w,
                      x2.x, x2.y, x2.z, x2.w, x3.x, x3.y, x3.z, x3.w};
#pragma unroll
      for (int j = 0; j < 16; ++j) abuf[j] = f2bf(xs[j]);
    }
    u16 bbuf[16];
    if (tid < 128) {
      const float* src = W + (size_t)(bn + brow) * 256 + k0 + bhalf * 16;
      float4 x0 = ((const float4*)src)[0], x1 = ((const float4*)src)[1];
      float4 x2 = ((const float4*)src)[2], x3 = ((const float4*)src)[3];
      float xs[16] = {x0.x, x0.y, x0.z, x0.w, x1.x, x1.y, x1.z, x1.w,
                      x2.x, x2.y, x2.z, x2.w, x3.x, x3.y, x3.z, x3.w};
#pragma unroll
      for (int j = 0; j < 16; ++j) bbuf[j] = f2bf(xs[j]);
    }
    __syncthreads();
    *(uint4*)&As[arow * 40 + ahalf * 16] = *(const uint4*)(abuf);
    *(uint4*)&As[arow * 40 + ahalf * 16 + 8] = *(const uint4*)(abuf + 8);
    if (tid < 128) {
      *(uint4*)&Bs[brow * 40 + bhalf * 16] = *(const uint4*)(bbuf);
      *(uint4*)&Bs[brow * 40 + bhalf * 16 + 8] = *(const uint4*)(bbuf + 8);
    }
    __syncthreads();
    s16x8 af[4], bfr[2];
#pragma unroll
    for (int mi = 0; mi < 4; ++mi)
      af[mi] = *(const s16x8*)&As[(wm * 64 + mi * 16 + l15) * 40 + l4 * 8];
#pragma unroll
    for (int ni = 0; ni < 2; ++ni)
      bfr[ni] = *(const s16x8*)&Bs[(wn * 32 + ni * 16 + l15) * 40 + l4 * 8];
#pragma unroll
    for (int mi = 0; mi < 4; ++mi)
#pragma unroll
      for (int ni = 0; ni < 2; ++ni)
        acc[mi][ni] = __builtin_amdgcn_mfma_f32_16x16x32_bf16(af[mi], bfr[ni], acc[mi][ni], 0, 0, 0);
  }
#pragma unroll
  for (int mi = 0; mi < 4; ++mi)
#pragma unroll
    for (int ni = 0; ni < 2; ++ni)
#pragma unroll
      for (int r = 0; r < 4; ++r) {
        int row = bm + wm * 64 + mi * 16 + l4 * 4 + r;
        int col = bn + wn * 32 + ni * 16 + l15;
        float val = acc[mi][ni][r] + bias[col];
        if (OUT_BF16) ((u16*)Cv)[(size_t)row * N + col] = f2bf(val);
        else          ((float*)Cv)[(size_t)row * N + col] = val;
      }
}

// ---------------------------------------------------------------------------
// f32 SIMT GEMM for xg. PERM: output column n holds gate j=(n&3)*16+(n>>2),
// i.e. xg[s][b][k*4+q] = gate q of hidden unit k (coalesced LSTM loads).
// ---------------------------------------------------------------------------
template<bool PERM>
__global__ __launch_bounds__(256) void gemm_nt(
    const float* __restrict__ A, const float* __restrict__ W,
    const float* __restrict__ b1, const float* __restrict__ b2,
    float* __restrict__ C, int N) {
  __shared__ float Asm[16][68];
  __shared__ float Bsm[16][68];
  const int tid = threadIdx.x;
  const int bm = blockIdx.x * 64;
  const int bn = blockIdx.y * 64;
  const int lr = tid >> 2;
  const int lc4 = (tid & 3) * 4;
  const int tm = (tid & 15) * 4;
  const int tn = (tid >> 4) * 4;
  float acc[4][4];
#pragma unroll
  for (int i = 0; i < 4; ++i)
#pragma unroll
    for (int j = 0; j < 4; ++j) acc[i][j] = 0.f;
  int wr = bn + lr;
  if (PERM) wr = ((wr & 3) * 16) + (wr >> 2);
  for (int k0 = 0; k0 < 256; k0 += 16) {
    float4 av = *reinterpret_cast<const float4*>(&A[(bm + lr) * 256 + k0 + lc4]);
    float4 bv = *reinterpret_cast<const float4*>(&W[wr * 256 + k0 + lc4]);
    __syncthreads();
    Asm[lc4 + 0][lr] = av.x; Asm[lc4 + 1][lr] = av.y; Asm[lc4 + 2][lr] = av.z; Asm[lc4 + 3][lr] = av.w;
    Bsm[lc4 + 0][lr] = bv.x; Bsm[lc4 + 1][lr] = bv.y; Bsm[lc4 + 2][lr] = bv.z; Bsm[lc4 + 3][lr] = bv.w;
    __syncthreads();
#pragma unroll
    for (int kk = 0; kk < 16; ++kk) {
      float4 a = *reinterpret_cast<const float4*>(&Asm[kk][tm]);
      float4 b = *reinterpret_cast<const float4*>(&Bsm[kk][tn]);
      float a_[4] = {a.x, a.y, a.z, a.w};
      float b_[4] = {b.x, b.y, b.z, b.w};
#pragma unroll
      for (int i = 0; i < 4; ++i)
#pragma unroll
        for (int j = 0; j < 4; ++j) acc[i][j] += a_[i] * b_[j];
    }
  }
#pragma unroll
  for (int i = 0; i < 4; ++i)
#pragma unroll
    for (int j = 0; j < 4; ++j) {
      int n = bn + tn + j;
      int jm = PERM ? ((n & 3) * 16) + (n >> 2) : n;
      float bias = b1[jm] + (b2 ? b2[jm] : 0.f);
      C[(size_t)(bm + tm + i) * N + n] = acc[i][j] + bias;
    }
}

// ---------------------------------------------------------------------------
// LSTM, register-matvec version. 8 blocks x 64. lane = b4*16 + k:
// lane owns h,c of unit k for batch blockIdx*4+b4 and all 4 gate rows of
// W_hh (64 regs). h broadcast via wave-synchronous LDS (1 write + 4 b128
// reads). xg prefetched 1 step deep (permuted layout -> one float4/lane).
// Heads write the packed coefficient buffer pc[p][s][8] =
// {rd0,rd1,rd2,wd0,wd1,wd2,rw0,rw1}. Identical arithmetic to verified r1.
// ---------------------------------------------------------------------------
__global__ __launch_bounds__(64) void lstm_kernel(
    const float* __restrict__ xg,    // [SEQ][32][64] permuted n=k*4+q
    const float* __restrict__ W_hh,  // [64][16]
    float* __restrict__ pc) {        // [64][256][8]
  const int lane = threadIdx.x;
  const int b4 = lane >> 4, k = lane & 15;
  const int b = blockIdx.x * 4 + b4;
  const int t = k >> 3, e = k & 7;
  const int p = b * 2 + t;
  __shared__ float hsh[4][16];
  float w[4][16];
#pragma unroll
  for (int q = 0; q < 4; ++q)
#pragma unroll
    for (int kk = 0; kk < 16; ++kk)
      w[q][kk] = W_hh[(q * 16 + k) * 16 + kk];
  float h = 0.f, c = 0.f;
  hsh[b4][k] = 0.f;
  float4 hb0 = *(const float4*)&hsh[b4][0];
  float4 hb1 = *(const float4*)&hsh[b4][4];
  float4 hb2 = *(const float4*)&hsh[b4][8];
  float4 hb3 = *(const float4*)&hsh[b4][12];
  float4 xv = *(const float4*)&xg[(size_t)b * 64 + k * 4];
  float* pcl = pc + (size_t)p * 2048 + e;

  for (int s = 0; s < SEQ; ++s) {
    const int sn = (s + 1 < SEQ) ? s + 1 : s;
    float4 xn = *(const float4*)&xg[(size_t)(sn * 32 + b) * 64 + k * 4];
    float hb[16];
    hb[0] = hb0.x; hb[1] = hb0.y; hb[2] = hb0.z; hb[3] = hb0.w;
    hb[4] = hb1.x; hb[5] = hb1.y; hb[6] = hb1.z; hb[7] = hb1.w;
    hb[8] = hb2.x; hb[9] = hb2.y; hb[10] = hb2.z; hb[11] = hb2.w;
    hb[12] = hb3.x; hb[13] = hb3.y; hb[14] = hb3.z; hb[15] = hb3.w;
    float g0 = xv.x, g1 = xv.y, g2 = xv.z, g3 = xv.w;
#pragma unroll
    for (int kk = 0; kk < 16; ++kk) {
      g0 += w[0][kk] * hb[kk];
      g1 += w[1][kk] * hb[kk];
      g2 += w[2][kk] * hb[kk];
      g3 += w[3][kk] * hb[kk];
    }
    c = sigm(g1) * c + sigm(g0) * tanh_(g2);
    h = sigm(g3) * tanh_(c);
    // broadcast new h (also serves the action heads)
    hsh[b4][k] = h;
    hb0 = *(const float4*)&hsh[b4][0];
    hb1 = *(const float4*)&hsh[b4][4];
    hb2 = *(const float4*)&hsh[b4][8];
    hb3 = *(const float4*)&hsh[b4][12];
    float nh[16];
    nh[0] = hb0.x; nh[1] = hb0.y; nh[2] = hb0.z; nh[3] = hb0.w;
    nh[4] = hb1.x; nh[5] = hb1.y; nh[6] = hb1.z; nh[7] = hb1.w;
    nh[8] = hb2.x; nh[9] = hb2.y; nh[10] = hb2.z; nh[11] = hb2.w;
    nh[12] = hb3.x; nh[13] = hb3.y; nh[14] = hb3.z; nh[15] = hb3.w;
    float av[8];
#pragma unroll
    for (int j = 0; j < 8; ++j) av[j] = (k & 8) ? nh[8 + j] : nh[j];
    float outv;
    if (e < 3) {
      float m = fmaxf(av[0], fmaxf(av[1], av[2]));
      float e0 = __expf(av[0] - m), e1 = __expf(av[1] - m), e2 = __expf(av[2] - m);
      float inv = 1.f / (e0 + e1 + e2);
      outv = (e == 0 ? e0 : (e == 1 ? e1 : e2)) * inv;
    } else if (e < 6) {
      float m = fmaxf(av[3], fmaxf(av[4], av[5]));
      float e0 = __expf(av[3] - m), e1 = __expf(av[4] - m), e2 = __expf(av[5] - m);
      float inv = 1.f / (e0 + e1 + e2);
      outv = (e == 3 ? e0 : (e == 4 ? e1 : e2)) * inv;
    } else {
      outv = sigm(e == 6 ? av[6] : av[7]);
    }
    pcl[(size_t)s * 8] = outv;
    xv = xn;
  }
}

// ---------------------------------------------------------------------------
// Position precompute, 4x unrolled with 4-step coefficient prefetch from pc.
// Identical arithmetic to the round-2-verified recurrence.
// ---------------------------------------------------------------------------
__global__ __launch_bounds__(64) void pos_kernel(
    const float* __restrict__ pc,      // [64][256][8]
    float* __restrict__ posW, float* __restrict__ posRs,
    float* __restrict__ out_rpos, float* __restrict__ out_wpos) {
  const int p = blockIdx.x, lane = threadIdx.x;
  float r0 = 0, r1 = 0, r2 = 0, r3 = 0, w0 = 0, w1 = 0, w2 = 0, w3 = 0;
  if (lane == 0) { r0 = 1.f; w0 = 1.f; }
  const float* pcb = pc + (size_t)p * 2048;
  float4 c0 = *(const float4*)&pcb[0];
  float4 c1 = *(const float4*)&pcb[4];
  for (int s0 = 0; s0 < SEQ; s0 += 4) {
    float4 pf[8];
#pragma unroll
    for (int u = 0; u < 4; ++u) {
      int sn = s0 + u + 1; if (sn > 255) sn = 255;
      pf[2 * u]     = *(const float4*)&pcb[sn * 8];
      pf[2 * u + 1] = *(const float4*)&pcb[sn * 8 + 4];
    }
#pragma unroll
    for (int u = 0; u < 4; ++u) {
      const int s = s0 + u;
      size_t ob = ((size_t)p * 256 + s) * 256 + lane * 4;
      *(float4*)(posW + ob) = make_float4(w0, w1, w2, w3);
      float rw0 = c1.z;
      *(float4*)(posRs + ob) = make_float4(r0 * rw0, r1 * rw0, r2 * rw0, r3 * rw0);
      const float crd0 = c0.x, crd1 = c0.y, crd2 = c0.z;
      const float cwd0 = c0.w, cwd1 = c1.x, cwd2 = c1.y;
      float rn  = __shfl(r0, (lane + 1) & 63, 64);
      float rpv = __shfl(r3, (lane + 63) & 63, 64);
      float nw0 = r1 * cwd0 + w0 * cwd1 + rpv * cwd2;
      float nr0 = r1 * crd0 + r0 * crd1 + rpv * crd2;
      float nw1 = r2 * cwd0 + w1 * cwd1 + r0 * cwd2;
      float nr1 = r2 * crd0 + r1 * crd1 + r0 * crd2;
      float nw2 = r3 * cwd0 + w2 * cwd1 + r1 * cwd2;
      float nr2 = r3 * crd0 + r2 * crd1 + r1 * crd2;
      float nw3 = rn * cwd0 + w3 * cwd1 + r2 * cwd2;
      float nr3 = rn * crd0 + r3 * crd1 + r2 * crd2;
      r0 = nr0; r1 = nr1; r2 = nr2; r3 = nr3;
      w0 = nw0; w1 = nw1; w2 = nw2; w3 = nw3;
      c0 = pf[2 * u]; c1 = pf[2 * u + 1];
    }
  }
  out_rpos[(size_t)(lane * 4 + 0) * 64 + p] = r0;
  out_rpos[(size_t)(lane * 4 + 1) * 64 + p] = r1;
  out_rpos[(size_t)(lane * 4 + 2) * 64 + p] = r2;
  out_rpos[(size_t)(lane * 4 + 3) * 64 + p] = r3;
  out_wpos[(size_t)(lane * 4 + 0) * 64 + p] = w0;
  out_wpos[(size_t)(lane * 4 + 1) * 64 + p] = w1;
  out_wpos[(size_t)(lane * 4 + 2) * 64 + p] = w2;
  out_wpos[(size_t)(lane * 4 + 3) * 64 + p] = w3;
}

// ---------------------------------------------------------------------------
// Batched per-pair GEMM with hi/lo bf16 compensation (3 MFMA terms ~ f32).
// MODE: 0 plain, 1 strict-lower x rw1[row] (skips all-upper tiles),
//       2 lower-incl (zero-fills all-upper tiles without compute).
// ---------------------------------------------------------------------------
template<bool TRANS_A, bool B_NT, int MODE, int OUTK, int BROW>
__global__ __launch_bounds__(256) void bgemm(
    const float* __restrict__ A, const float* __restrict__ B,
    const float* __restrict__ pc, float* __restrict__ C,
    size_t sA, size_t sB) {
  __shared__ u16 Ah[128 * 40], Al[128 * 40], Bh[64 * 40], Bl[64 * 40];
  const int p = blockIdx.z;
  const int bm = blockIdx.y * 128, bn = blockIdx.x * 64;
  const int tid = threadIdx.x, wv = tid >> 6, lane = tid & 63;
  const int wm = wv >> 1, wn = wv & 1, l15 = lane & 15, l4 = lane >> 4;
  const int b = p >> 1, t = p & 1;

  if (MODE == 1 && bn >= bm + 128) return;  // never read downstream
  if (MODE == 2 && bn >= bm + 128) {        // all strictly-upper: zeros
#pragma unroll
    for (int mi = 0; mi < 4; ++mi)
#pragma unroll
      for (int ni = 0; ni < 2; ++ni)
#pragma unroll
        for (int r = 0; r < 4; ++r) {
          int row = bm + wm * 64 + mi * 16 + l4 * 4 + r;
          int col = bn + wn * 32 + ni * 16 + l15;
          C[(size_t)p * 65536 + (size_t)row * 256 + col] = 0.f;
        }
    return;
  }

  const float* Ap = A + (size_t)p * sA;
  const float* Bp = B + (size_t)p * sB;
  f32x4 acc[4][2] = {};

  for (int k0 = 0; k0 < 256; k0 += 32) {
    float xa[16];
    if (!TRANS_A) {
      const int m = tid >> 1, kq = (tid & 1) * 16;
      const float* src = Ap + (size_t)(bm + m) * 256 + k0 + kq;
#pragma unroll
      for (int j = 0; j < 4; ++j) *(float4*)(xa + j * 4) = ((const float4*)src)[j];
    } else {
      const int kr = tid >> 3, mq = (tid & 7) * 16;
      const float* src = Ap + (size_t)(k0 + kr) * 256 + bm + mq;
#pragma unroll
      for (int j = 0; j < 4; ++j) *(float4*)(xa + j * 4) = ((const float4*)src)[j];
    }
    u16 ah[16], al[16];
#pragma unroll
    for (int j = 0; j < 16; ++j) {
      u16 hh = f2bf(xa[j]);
      ah[j] = hh; al[j] = f2bf(xa[j] - bf2f(hh));
    }
    float xb[8];
    if (B_NT) {
      const int n = tid >> 2, kq = (tid & 3) * 8;
      const float* src = Bp + (size_t)(bn + n) * 256 + k0 + kq;
      *(float4*)(xb) = ((const float4*)src)[0];
      *(float4*)(xb + 4) = ((const float4*)src)[1];
    } else {
      const int kr = tid >> 3, nq = (tid & 7) * 8;
      const float* src = Bp + (size_t)(k0 + kr) * BROW + bn + nq;
      *(float4*)(xb) = ((const float4*)src)[0];
      *(float4*)(xb + 4) = ((const float4*)src)[1];
    }
    u16 bh[8], bl[8];
#pragma unroll
    for (int j = 0; j < 8; ++j) {
      u16 hh = f2bf(xb[j]);
      bh[j] = hh; bl[j] = f2bf(xb[j] - bf2f(hh));
    }
    __syncthreads();
    if (!TRANS_A) {
      const int m = tid >> 1, kq = (tid & 1) * 16;
      *(uint4*)&Ah[m * 40 + kq]     = *(const uint4*)(ah);
      *(uint4*)&Ah[m * 40 + kq + 8] = *(const uint4*)(ah + 8);
      *(uint4*)&Al[m * 40 + kq]     = *(const uint4*)(al);
      *(uint4*)&Al[m * 40 + kq + 8] = *(const uint4*)(al + 8);
    } else {
      const int kr = tid >> 3, mq = (tid & 7) * 16;
#pragma unroll
      for (int j = 0; j < 16; ++j) {
        Ah[(mq + j) * 40 + kr] = ah[j];
        Al[(mq + j) * 40 + kr] = al[j];
      }
    }
    if (B_NT) {
      const int n = tid >> 2, kq = (tid & 3) * 8;
      *(uint4*)&Bh[n * 40 + kq] = *(const uint4*)(bh);
      *(uint4*)&Bl[n * 40 + kq] = *(const uint4*)(bl);
    } else {
      const int kr = tid >> 3, nq = (tid & 7) * 8;
#pragma unroll
      for (int j = 0; j < 8; ++j) {
        Bh[(nq + j) * 40 + kr] = bh[j];
        Bl[(nq + j) * 40 + kr] = bl[j];
      }
    }
    __syncthreads();
    s16x8 fah[4], fal[4], fbh[2], fbl[2];
#pragma unroll
    for (int mi = 0; mi < 4; ++mi) {
      fah[mi] = *(const s16x8*)&Ah[(wm * 64 + mi * 16 + l15) * 40 + l4 * 8];
      fal[mi] = *(const s16x8*)&Al[(wm * 64 + mi * 16 + l15) * 40 + l4 * 8];
    }
#pragma unroll
    for (int ni = 0; ni < 2; ++ni) {
      fbh[ni] = *(const s16x8*)&Bh[(wn * 32 + ni * 16 + l15) * 40 + l4 * 8];
      fbl[ni] = *(const s16x8*)&Bl[(wn * 32 + ni * 16 + l15) * 40 + l4 * 8];
    }
#pragma unroll
    for (int mi = 0; mi < 4; ++mi)
#pragma unroll
      for (int ni = 0; ni < 2; ++ni) {
        acc[mi][ni] = __builtin_amdgcn_mfma_f32_16x16x32_bf16(fah[mi], fbh[ni], acc[mi][ni], 0, 0, 0);
        acc[mi][ni] = __builtin_amdgcn_mfma_f32_16x16x32_bf16(fah[mi], fbl[ni], acc[mi][ni], 0, 0, 0);
        acc[mi][ni] = __builtin_amdgcn_mfma_f32_16x16x32_bf16(fal[mi], fbh[ni], acc[mi][ni], 0, 0, 0);
      }
  }
#pragma unroll
  for (int mi = 0; mi < 4; ++mi)
#pragma unroll
    for (int ni = 0; ni < 2; ++ni)
#pragma unroll
      for (int r = 0; r < 4; ++r) {
        int row = bm + wm * 64 + mi * 16 + l4 * 4 + r;
        int col = bn + wn * 32 + ni * 16 + l15;
        float v = acc[mi][ni][r];
        if (MODE == 1) v = (col < row) ? v * pc[((size_t)p * 256 + row) * 8 + 7] : 0.f;
        if (MODE == 2) v = (col <= row) ? v : 0.f;
        if (OUTK == 0)      C[(size_t)p * 65536 + (size_t)row * 256 + col] = v;
        else if (OUTK == 1) C[((size_t)(row * 32 + b)) * 256 + t * 128 + col] = v;
        else                C[((size_t)row * 64 + p) * 128 + col] = v;
      }
}

// ---------------------------------------------------------------------------
// Blocked triangular solve (I + L) delta = rw1 * v.  Grid 128 = (pair, chalf).
// ---------------------------------------------------------------------------
__global__ __launch_bounds__(256) void solve_kernel(
    const float* __restrict__ L,        // [64][256][256] strict-lower, rw1-scaled
    const u16* __restrict__ values,     // bf16 [8192][256]
    const float* __restrict__ pc,       // [64][256][8]
    float* __restrict__ delta) {        // [64][256][128]
  const int p = blockIdx.x >> 1, half = blockIdx.x & 1;
  const int b = p >> 1, t = p & 1;
  const int tid = threadIdx.x, w = tid >> 6, lane = tid & 63;
  __shared__ float ds[256][64];
  __shared__ float Ps[32][64];
  __shared__ float Db[32][33];
  const float* Lp = L + (size_t)p * 65536;

  for (int k = 0; k < 8; ++k) {
    const int s0 = k * 32;
    float acc[8];
#pragma unroll
    for (int i = 0; i < 8; ++i) {
      const int s = s0 + w * 8 + i;
      float rv = bf2f(values[((size_t)(s * 32 + b)) * 256 + t * 128 + half * 64 + lane]);
      acc[i] = rv * pc[((size_t)p * 256 + s) * 8 + 7];
    }
    const float* Lr0 = Lp + (size_t)(s0 + w * 8) * 256;
#pragma unroll 4
    for (int j = 0; j < s0; ++j) {
      float dj = ds[j][lane];
#pragma unroll
      for (int i = 0; i < 8; ++i) acc[i] -= Lr0[(size_t)i * 256 + j] * dj;
    }
    {
      const int r = tid >> 3, q0 = (tid & 7) * 4;
      float4 dv = *(const float4*)(Lp + (size_t)(s0 + r) * 256 + s0 + q0);
      Db[r][q0] = dv.x; Db[r][q0 + 1] = dv.y; Db[r][q0 + 2] = dv.z; Db[r][q0 + 3] = dv.w;
    }
#pragma unroll
    for (int i = 0; i < 8; ++i) Ps[w * 8 + i][lane] = acc[i];
    __syncthreads();
    if (w == 0) {
      float d[32];
#pragma unroll
      for (int r = 0; r < 32; ++r) {
        float xa = Ps[r][lane], xb = 0.f;
#pragma unroll
        for (int q = 0; q < 32; ++q) {
          if (q < r) {
            if (q & 1) xb -= Db[r][q] * d[q];
            else       xa -= Db[r][q] * d[q];
          }
        }
        float x = xa + xb;
        d[r] = x;
        ds[s0 + r][lane] = x;
        delta[((size_t)p * 256 + s0 + r) * 128 + half * 64 + lane] = x;
      }
    }
    __syncthreads();
  }
}

// ---------------------------------------------------------------------------
extern "C" void kernel_launch(void* const* d_in, const int* in_sizes, int n_in,
                              void* d_out, int out_size, void* d_ws, size_t ws_size,
                              hipStream_t stream) {
  const float* inputs = (const float*)d_in[0];
  const float* W_ih = (const float*)d_in[2];
  const float* W_hh = (const float*)d_in[3];
  const float* b_ih = (const float*)d_in[4];
  const float* b_hh = (const float*)d_in[5];
  const float* W_val = (const float*)d_in[6];
  const float* b_val = (const float*)d_in[7];
  const float* W_out = (const float*)d_in[8];
  const float* b_out = (const float*)d_in[9];

  float* out = (float*)d_out;
  float* out_tape = out + 2097152;
  float* out_rpos = out + 4194304;
  float* out_wpos = out + 4210688;

  char* ws = (char*)d_ws;
  float* posW      = (float*)(ws);                    // 16 MB  [64][256][256]
  float* posRs     = (float*)(ws + 16777216);         // 16 MB  (reused: reads_f32)
  float* LHm       = (float*)(ws + 33554432);         // 16 MB  (L, then Hm)
  u16*   values_bf = (u16*)  (ws + 50331648);         //  4 MB
  float* xg        = (float*)(ws + 54525952);         //  2 MB (dead after lstm)
  float* delta     = (float*)(ws + 54525952);         //  8 MB (aliases xg)
  float* pcb       = (float*)(ws + 62914560);         // 512 KB [64][256][8]
  float* reads_f32 = posRs;

  // 1. values (bf16) = inputs @ W_val^T + b_val
  gemm_mfma<false, true><<<dim3(64, 4), 256, 0, stream>>>(inputs, W_val, b_val, values_bf, 256);
  // 2. xg (f32, permuted cols) = inputs @ W_ih^T + (b_ih + b_hh)
  gemm_nt<true><<<dim3(128, 1), 256, 0, stream>>>(inputs, W_ih, b_ih, b_hh, xg, 64);
  // 3. LSTM -> packed coefficients pc
  lstm_kernel<<<8, 64, 0, stream>>>(xg, W_hh, pcb);
  // 4. position trajectories
  pos_kernel<<<64, 64, 0, stream>>>(pcb, posW, posRs, out_rpos, out_wpos);
  // 5. L = rw1 (.) strict_tril(posW posW^T)
  bgemm<false, true, 1, 0, 256><<<dim3(4, 2, 64), 256, 0, stream>>>(
      posW, posW, pcb, LHm, 65536, 65536);
  // 6. blocked triangular solve -> delta
  solve_kernel<<<128, 256, 0, stream>>>(LHm, values_bf, pcb, delta);
  // 7. Hm = tril_incl(posRs posW^T)   (overwrites L)
  bgemm<false, true, 2, 0, 256><<<dim3(4, 2, 64), 256, 0, stream>>>(
      posRs, posW, pcb, LHm, 65536, 65536);
  // 8. reads = Hm @ delta   (reads layout [s*32+b][256])
  bgemm<false, false, 0, 1, 128><<<dim3(2, 2, 64), 256, 0, stream>>>(
      LHm, delta, pcb, reads_f32, 65536, 32768);
  // 9. out_tape = posW^T @ delta
  bgemm<true, false, 0, 2, 128><<<dim3(2, 2, 64), 256, 0, stream>>>(
      posW, delta, pcb, out_tape, 65536, 32768);
  // 10. outputs = reads @ W_out^T + b_out
  gemm_mfma<false, false><<<dim3(64, 4), 256, 0, stream>>>(reads_f32, W_out, b_out, out, 256);
}

// Round 6
// 453.468 us; speedup vs baseline: 1.5847x; 1.1530x over previous
//
#include <hip/hip_runtime.h>

#define SEQ    256
#define BATCH  32
#define NT     2
#define DIM    128
#define LTAPE  256

typedef float f32x4 __attribute__((ext_vector_type(4)));
typedef short s16x8 __attribute__((ext_vector_type(8)));
typedef unsigned int u32;
typedef unsigned short u16;

__device__ __forceinline__ float sigm(float x) { return 1.f / (1.f + __expf(-x)); }
__device__ __forceinline__ float tanh_(float x) { float e = __expf(2.f * x); return 1.f - 2.f / (e + 1.f); }
__device__ __forceinline__ u16 f2bf(float x) {
  u32 u = __builtin_bit_cast(u32, x);
  u32 r = (u + 0x7fffu + ((u >> 16) & 1u)) >> 16;
  return (u16)r;
}
__device__ __forceinline__ float bf2f(u16 b) {
  u32 u = ((u32)b) << 16; return __builtin_bit_cast(float, u);
}

// ---------------------------------------------------------------------------
// bf16 MFMA GEMM (verified): C[M][N] = A[M][256] @ W[N][256]^T + bias.
// ---------------------------------------------------------------------------
template<bool A_BF16, bool OUT_BF16>
__global__ __launch_bounds__(256) void gemm_mfma(
    const void* __restrict__ Av, const float* __restrict__ W,
    const float* __restrict__ bias, void* __restrict__ Cv, int N) {
  __shared__ u16 As[128 * 40];
  __shared__ u16 Bs[64 * 40];
  const int tid = threadIdx.x;
  const int bm = blockIdx.x * 128, bn = blockIdx.y * 64;
  const int wv = tid >> 6, lane = tid & 63;
  const int wm = wv >> 1, wn = wv & 1;
  const int l15 = lane & 15, l4 = lane >> 4;
  f32x4 acc[4][2] = {};
  const int arow = tid >> 1, ahalf = tid & 1;
  const int brow = (tid & 127) >> 1, bhalf = tid & 1;

  for (int k0 = 0; k0 < 256; k0 += 32) {
    u16 abuf[16];
    if (A_BF16) {
      const u16* A = (const u16*)Av;
      const uint4* p = (const uint4*)(A + (size_t)(bm + arow) * 256 + k0 + ahalf * 16);
      *(uint4*)(abuf) = p[0]; *(uint4*)(abuf + 8) = p[1];
    } else {
      const float* A = (const float*)Av;
      const float* src = A + (size_t)(bm + arow) * 256 + k0 + ahalf * 16;
      float4 x0 = ((const float4*)src)[0], x1 = ((const float4*)src)[1];
      float4 x2 = ((const float4*)src)[2], x3 = ((const float4*)src)[3];
      float xs[16] = {x0.x, x0.y, x0.z, x0.w, x1.x, x1.y, x1.z, x1.w,
                      x2.x, x2.y, x2.z, x2.w, x3.x, x3.y, x3.z, x3.w};
#pragma unroll
      for (int j = 0; j < 16; ++j) abuf[j] = f2bf(xs[j]);
    }
    u16 bbuf[16];
    if (tid < 128) {
      const float* src = W + (size_t)(bn + brow) * 256 + k0 + bhalf * 16;
      float4 x0 = ((const float4*)src)[0], x1 = ((const float4*)src)[1];
      float4 x2 = ((const float4*)src)[2], x3 = ((const float4*)src)[3];
      float xs[16] = {x0.x, x0.y, x0.z, x0.w, x1.x, x1.y, x1.z, x1.w,
                      x2.x, x2.y, x2.z, x2.w, x3.x, x3.y, x3.z, x3.w};
#pragma unroll
      for (int j = 0; j < 16; ++j) bbuf[j] = f2bf(xs[j]);
    }
    __syncthreads();
    *(uint4*)&As[arow * 40 + ahalf * 16] = *(const uint4*)(abuf);
    *(uint4*)&As[arow * 40 + ahalf * 16 + 8] = *(const uint4*)(abuf + 8);
    if (tid < 128) {
      *(uint4*)&Bs[brow * 40 + bhalf * 16] = *(const uint4*)(bbuf);
      *(uint4*)&Bs[brow * 40 + bhalf * 16 + 8] = *(const uint4*)(bbuf + 8);
    }
    __syncthreads();
    s16x8 af[4], bfr[2];
#pragma unroll
    for (int mi = 0; mi < 4; ++mi)
      af[mi] = *(const s16x8*)&As[(wm * 64 + mi * 16 + l15) * 40 + l4 * 8];
#pragma unroll
    for (int ni = 0; ni < 2; ++ni)
      bfr[ni] = *(const s16x8*)&Bs[(wn * 32 + ni * 16 + l15) * 40 + l4 * 8];
#pragma unroll
    for (int mi = 0; mi < 4; ++mi)
#pragma unroll
      for (int ni = 0; ni < 2; ++ni)
        acc[mi][ni] = __builtin_amdgcn_mfma_f32_16x16x32_bf16(af[mi], bfr[ni], acc[mi][ni], 0, 0, 0);
  }
#pragma unroll
  for (int mi = 0; mi < 4; ++mi)
#pragma unroll
    for (int ni = 0; ni < 2; ++ni)
#pragma unroll
      for (int r = 0; r < 4; ++r) {
        int row = bm + wm * 64 + mi * 16 + l4 * 4 + r;
        int col = bn + wn * 32 + ni * 16 + l15;
        float val = acc[mi][ni][r] + bias[col];
        if (OUT_BF16) ((u16*)Cv)[(size_t)row * N + col] = f2bf(val);
        else          ((float*)Cv)[(size_t)row * N + col] = val;
      }
}

// ---------------------------------------------------------------------------
// f32 SIMT GEMM for xg. PERM: output column n holds gate j=(n&3)*16+(n>>2).
// ---------------------------------------------------------------------------
template<bool PERM>
__global__ __launch_bounds__(256) void gemm_nt(
    const float* __restrict__ A, const float* __restrict__ W,
    const float* __restrict__ b1, const float* __restrict__ b2,
    float* __restrict__ C, int N) {
  __shared__ float Asm[16][68];
  __shared__ float Bsm[16][68];
  const int tid = threadIdx.x;
  const int bm = blockIdx.x * 64;
  const int bn = blockIdx.y * 64;
  const int lr = tid >> 2;
  const int lc4 = (tid & 3) * 4;
  const int tm = (tid & 15) * 4;
  const int tn = (tid >> 4) * 4;
  float acc[4][4];
#pragma unroll
  for (int i = 0; i < 4; ++i)
#pragma unroll
    for (int j = 0; j < 4; ++j) acc[i][j] = 0.f;
  int wr = bn + lr;
  if (PERM) wr = ((wr & 3) * 16) + (wr >> 2);
  for (int k0 = 0; k0 < 256; k0 += 16) {
    float4 av = *reinterpret_cast<const float4*>(&A[(bm + lr) * 256 + k0 + lc4]);
    float4 bv = *reinterpret_cast<const float4*>(&W[wr * 256 + k0 + lc4]);
    __syncthreads();
    Asm[lc4 + 0][lr] = av.x; Asm[lc4 + 1][lr] = av.y; Asm[lc4 + 2][lr] = av.z; Asm[lc4 + 3][lr] = av.w;
    Bsm[lc4 + 0][lr] = bv.x; Bsm[lc4 + 1][lr] = bv.y; Bsm[lc4 + 2][lr] = bv.z; Bsm[lc4 + 3][lr] = bv.w;
    __syncthreads();
#pragma unroll
    for (int kk = 0; kk < 16; ++kk) {
      float4 a = *reinterpret_cast<const float4*>(&Asm[kk][tm]);
      float4 b = *reinterpret_cast<const float4*>(&Bsm[kk][tn]);
      float a_[4] = {a.x, a.y, a.z, a.w};
      float b_[4] = {b.x, b.y, b.z, b.w};
#pragma unroll
      for (int i = 0; i < 4; ++i)
#pragma unroll
        for (int j = 0; j < 4; ++j) acc[i][j] += a_[i] * b_[j];
    }
  }
#pragma unroll
  for (int i = 0; i < 4; ++i)
#pragma unroll
    for (int j = 0; j < 4; ++j) {
      int n = bn + tn + j;
      int jm = PERM ? ((n & 3) * 16) + (n >> 2) : n;
      float bias = b1[jm] + (b2 ? b2[jm] : 0.f);
      C[(size_t)(bm + tm + i) * N + n] = acc[i][j] + bias;
    }
}

// ---------------------------------------------------------------------------
// LSTM core only. 8 blocks x 64; lane = b4*16 + k owns h,c of unit k for
// batch blockIdx*4+b4 and all 4 gate rows of W_hh in registers.
// h-broadcast via 16 __shfl (no LDS); xg prefetched 4 steps deep; heads
// deferred (store raw h). Identical recurrence arithmetic to verified r1.
// ---------------------------------------------------------------------------
__global__ __launch_bounds__(64) void lstm_kernel(
    const float* __restrict__ xg,    // [SEQ][32][64] permuted n=k*4+q
    const float* __restrict__ W_hh,  // [64][16]
    float* __restrict__ hout) {      // [SEQ][32][16]
  const int lane = threadIdx.x;
  const int b4 = lane >> 4, k = lane & 15;
  const int b = blockIdx.x * 4 + b4;
  const int lbase = lane & 48;
  float w[4][16];
#pragma unroll
  for (int q = 0; q < 4; ++q)
#pragma unroll
    for (int kk = 0; kk < 16; ++kk)
      w[q][kk] = W_hh[(q * 16 + k) * 16 + kk];
  float h = 0.f, c = 0.f;
  const float* xb = xg + (size_t)b * 64 + k * 4;
  float4 xA = *(const float4*)(xb + (size_t)0 * 2048);
  float4 xB = *(const float4*)(xb + (size_t)1 * 2048);
  float4 xC = *(const float4*)(xb + (size_t)2 * 2048);
  float4 xD = *(const float4*)(xb + (size_t)3 * 2048);

#define LSTM_STEP(S, XV)                                                     \
  {                                                                          \
    float hb[16];                                                            \
    _Pragma("unroll") for (int kk = 0; kk < 16; ++kk)                        \
      hb[kk] = __shfl(h, lbase + kk, 64);                                    \
    float g0 = XV.x, g1 = XV.y, g2 = XV.z, g3 = XV.w;                        \
    _Pragma("unroll") for (int kk = 0; kk < 16; ++kk) {                      \
      g0 += w[0][kk] * hb[kk];                                               \
      g1 += w[1][kk] * hb[kk];                                               \
      g2 += w[2][kk] * hb[kk];                                               \
      g3 += w[3][kk] * hb[kk];                                               \
    }                                                                        \
    c = sigm(g1) * c + sigm(g0) * tanh_(g2);                                 \
    h = sigm(g3) * tanh_(c);                                                 \
    hout[(size_t)((S) * 32 + b) * 16 + k] = h;                               \
  }

  for (int s0 = 0; s0 < SEQ; s0 += 4) {
    int p4 = s0 + 4; if (p4 > 255) p4 = 255;
    int p5 = s0 + 5; if (p5 > 255) p5 = 255;
    int p6 = s0 + 6; if (p6 > 255) p6 = 255;
    int p7 = s0 + 7; if (p7 > 255) p7 = 255;
    float4 nA = *(const float4*)(xb + (size_t)p4 * 2048);
    float4 nB = *(const float4*)(xb + (size_t)p5 * 2048);
    float4 nC = *(const float4*)(xb + (size_t)p6 * 2048);
    float4 nD = *(const float4*)(xb + (size_t)p7 * 2048);
    LSTM_STEP(s0 + 0, xA);
    LSTM_STEP(s0 + 1, xB);
    LSTM_STEP(s0 + 2, xC);
    LSTM_STEP(s0 + 3, xD);
    xA = nA; xB = nB; xC = nC; xD = nD;
  }
#undef LSTM_STEP
}

// ---------------------------------------------------------------------------
// Action heads: softmax/sigmoid from raw h -> pc[p][s][8] =
// {rd0,rd1,rd2,wd0,wd1,wd2,rw0,rw1}. idx == p*2048 + s*8 + e.
// ---------------------------------------------------------------------------
__global__ __launch_bounds__(256) void head_kernel(
    const float* __restrict__ hout,  // [SEQ][32][16]
    float* __restrict__ pc) {        // [64][256][8]
  const int idx = blockIdx.x * 256 + threadIdx.x;
  const int e = idx & 7, s = (idx >> 3) & 255, p = idx >> 11;
  const int b = p >> 1, t = p & 1;
  const float* hp = hout + ((size_t)(s * 32 + b)) * 16 + t * 8;
  float outv;
  if (e < 3) {
    float a0 = hp[0], a1 = hp[1], a2 = hp[2];
    float m = fmaxf(a0, fmaxf(a1, a2));
    float e0 = __expf(a0 - m), e1 = __expf(a1 - m), e2 = __expf(a2 - m);
    float inv = 1.f / (e0 + e1 + e2);
    outv = (e == 0 ? e0 : (e == 1 ? e1 : e2)) * inv;
  } else if (e < 6) {
    float a3 = hp[3], a4 = hp[4], a5 = hp[5];
    float m = fmaxf(a3, fmaxf(a4, a5));
    float e0 = __expf(a3 - m), e1 = __expf(a4 - m), e2 = __expf(a5 - m);
    float inv = 1.f / (e0 + e1 + e2);
    outv = (e == 3 ? e0 : (e == 4 ? e1 : e2)) * inv;
  } else {
    outv = sigm(hp[e]);
  }
  pc[idx] = outv;
}

// ---------------------------------------------------------------------------
// Position precompute, 4x unrolled with 4-step coefficient prefetch from pc.
// ---------------------------------------------------------------------------
__global__ __launch_bounds__(64) void pos_kernel(
    const float* __restrict__ pc,      // [64][256][8]
    float* __restrict__ posW, float* __restrict__ posRs,
    float* __restrict__ out_rpos, float* __restrict__ out_wpos) {
  const int p = blockIdx.x, lane = threadIdx.x;
  float r0 = 0, r1 = 0, r2 = 0, r3 = 0, w0 = 0, w1 = 0, w2 = 0, w3 = 0;
  if (lane == 0) { r0 = 1.f; w0 = 1.f; }
  const float* pcb = pc + (size_t)p * 2048;
  float4 c0 = *(const float4*)&pcb[0];
  float4 c1 = *(const float4*)&pcb[4];
  for (int s0 = 0; s0 < SEQ; s0 += 4) {
    float4 pf[8];
#pragma unroll
    for (int u = 0; u < 4; ++u) {
      int sn = s0 + u + 1; if (sn > 255) sn = 255;
      pf[2 * u]     = *(const float4*)&pcb[sn * 8];
      pf[2 * u + 1] = *(const float4*)&pcb[sn * 8 + 4];
    }
#pragma unroll
    for (int u = 0; u < 4; ++u) {
      const int s = s0 + u;
      size_t ob = ((size_t)p * 256 + s) * 256 + lane * 4;
      *(float4*)(posW + ob) = make_float4(w0, w1, w2, w3);
      float rw0 = c1.z;
      *(float4*)(posRs + ob) = make_float4(r0 * rw0, r1 * rw0, r2 * rw0, r3 * rw0);
      const float crd0 = c0.x, crd1 = c0.y, crd2 = c0.z;
      const float cwd0 = c0.w, cwd1 = c1.x, cwd2 = c1.y;
      float rn  = __shfl(r0, (lane + 1) & 63, 64);
      float rpv = __shfl(r3, (lane + 63) & 63, 64);
      float nw0 = r1 * cwd0 + w0 * cwd1 + rpv * cwd2;
      float nr0 = r1 * crd0 + r0 * crd1 + rpv * crd2;
      float nw1 = r2 * cwd0 + w1 * cwd1 + r0 * cwd2;
      float nr1 = r2 * crd0 + r1 * crd1 + r0 * crd2;
      float nw2 = r3 * cwd0 + w2 * cwd1 + r1 * cwd2;
      float nr2 = r3 * crd0 + r2 * crd1 + r1 * crd2;
      float nw3 = rn * cwd0 + w3 * cwd1 + r2 * cwd2;
      float nr3 = rn * crd0 + r3 * crd1 + r2 * crd2;
      r0 = nr0; r1 = nr1; r2 = nr2; r3 = nr3;
      w0 = nw0; w1 = nw1; w2 = nw2; w3 = nw3;
      c0 = pf[2 * u]; c1 = pf[2 * u + 1];
    }
  }
  out_rpos[(size_t)(lane * 4 + 0) * 64 + p] = r0;
  out_rpos[(size_t)(lane * 4 + 1) * 64 + p] = r1;
  out_rpos[(size_t)(lane * 4 + 2) * 64 + p] = r2;
  out_rpos[(size_t)(lane * 4 + 3) * 64 + p] = r3;
  out_wpos[(size_t)(lane * 4 + 0) * 64 + p] = w0;
  out_wpos[(size_t)(lane * 4 + 1) * 64 + p] = w1;
  out_wpos[(size_t)(lane * 4 + 2) * 64 + p] = w2;
  out_wpos[(size_t)(lane * 4 + 3) * 64 + p] = w3;
}

// ---------------------------------------------------------------------------
// Batched per-pair GEMM with hi/lo bf16 compensation (3 MFMA terms ~ f32).
// MODE: 0 plain, 1 strict-lower x rw1[row] (skips all-upper tiles),
//       2 lower-incl (zero-fills all-upper tiles without compute).
// ---------------------------------------------------------------------------
template<bool TRANS_A, bool B_NT, int MODE, int OUTK, int BROW>
__global__ __launch_bounds__(256) void bgemm(
    const float* __restrict__ A, const float* __restrict__ B,
    const float* __restrict__ pc, float* __restrict__ C,
    size_t sA, size_t sB) {
  __shared__ u16 Ah[128 * 40], Al[128 * 40], Bh[64 * 40], Bl[64 * 40];
  const int p = blockIdx.z;
  const int bm = blockIdx.y * 128, bn = blockIdx.x * 64;
  const int tid = threadIdx.x, wv = tid >> 6, lane = tid & 63;
  const int wm = wv >> 1, wn = wv & 1, l15 = lane & 15, l4 = lane >> 4;
  const int b = p >> 1, t = p & 1;

  if (MODE == 1 && bn >= bm + 128) return;
  if (MODE == 2 && bn >= bm + 128) {
#pragma unroll
    for (int mi = 0; mi < 4; ++mi)
#pragma unroll
      for (int ni = 0; ni < 2; ++ni)
#pragma unroll
        for (int r = 0; r < 4; ++r) {
          int row = bm + wm * 64 + mi * 16 + l4 * 4 + r;
          int col = bn + wn * 32 + ni * 16 + l15;
          C[(size_t)p * 65536 + (size_t)row * 256 + col] = 0.f;
        }
    return;
  }

  const float* Ap = A + (size_t)p * sA;
  const float* Bp = B + (size_t)p * sB;
  f32x4 acc[4][2] = {};

  for (int k0 = 0; k0 < 256; k0 += 32) {
    float xa[16];
    if (!TRANS_A) {
      const int m = tid >> 1, kq = (tid & 1) * 16;
      const float* src = Ap + (size_t)(bm + m) * 256 + k0 + kq;
#pragma unroll
      for (int j = 0; j < 4; ++j) *(float4*)(xa + j * 4) = ((const float4*)src)[j];
    } else {
      const int kr = tid >> 3, mq = (tid & 7) * 16;
      const float* src = Ap + (size_t)(k0 + kr) * 256 + bm + mq;
#pragma unroll
      for (int j = 0; j < 4; ++j) *(float4*)(xa + j * 4) = ((const float4*)src)[j];
    }
    u16 ah[16], al[16];
#pragma unroll
    for (int j = 0; j < 16; ++j) {
      u16 hh = f2bf(xa[j]);
      ah[j] = hh; al[j] = f2bf(xa[j] - bf2f(hh));
    }
    float xb[8];
    if (B_NT) {
      const int n = tid >> 2, kq = (tid & 3) * 8;
      const float* src = Bp + (size_t)(bn + n) * 256 + k0 + kq;
      *(float4*)(xb) = ((const float4*)src)[0];
      *(float4*)(xb + 4) = ((const float4*)src)[1];
    } else {
      const int kr = tid >> 3, nq = (tid & 7) * 8;
      const float* src = Bp + (size_t)(k0 + kr) * BROW + bn + nq;
      *(float4*)(xb) = ((const float4*)src)[0];
      *(float4*)(xb + 4) = ((const float4*)src)[1];
    }
    u16 bh[8], bl[8];
#pragma unroll
    for (int j = 0; j < 8; ++j) {
      u16 hh = f2bf(xb[j]);
      bh[j] = hh; bl[j] = f2bf(xb[j] - bf2f(hh));
    }
    __syncthreads();
    if (!TRANS_A) {
      const int m = tid >> 1, kq = (tid & 1) * 16;
      *(uint4*)&Ah[m * 40 + kq]     = *(const uint4*)(ah);
      *(uint4*)&Ah[m * 40 + kq + 8] = *(const uint4*)(ah + 8);
      *(uint4*)&Al[m * 40 + kq]     = *(const uint4*)(al);
      *(uint4*)&Al[m * 40 + kq + 8] = *(const uint4*)(al + 8);
    } else {
      const int kr = tid >> 3, mq = (tid & 7) * 16;
#pragma unroll
      for (int j = 0; j < 16; ++j) {
        Ah[(mq + j) * 40 + kr] = ah[j];
        Al[(mq + j) * 40 + kr] = al[j];
      }
    }
    if (B_NT) {
      const int n = tid >> 2, kq = (tid & 3) * 8;
      *(uint4*)&Bh[n * 40 + kq] = *(const uint4*)(bh);
      *(uint4*)&Bl[n * 40 + kq] = *(const uint4*)(bl);
    } else {
      const int kr = tid >> 3, nq = (tid & 7) * 8;
#pragma unroll
      for (int j = 0; j < 8; ++j) {
        Bh[(nq + j) * 40 + kr] = bh[j];
        Bl[(nq + j) * 40 + kr] = bl[j];
      }
    }
    __syncthreads();
    s16x8 fah[4], fal[4], fbh[2], fbl[2];
#pragma unroll
    for (int mi = 0; mi < 4; ++mi) {
      fah[mi] = *(const s16x8*)&Ah[(wm * 64 + mi * 16 + l15) * 40 + l4 * 8];
      fal[mi] = *(const s16x8*)&Al[(wm * 64 + mi * 16 + l15) * 40 + l4 * 8];
    }
#pragma unroll
    for (int ni = 0; ni < 2; ++ni) {
      fbh[ni] = *(const s16x8*)&Bh[(wn * 32 + ni * 16 + l15) * 40 + l4 * 8];
      fbl[ni] = *(const s16x8*)&Bl[(wn * 32 + ni * 16 + l15) * 40 + l4 * 8];
    }
#pragma unroll
    for (int mi = 0; mi < 4; ++mi)
#pragma unroll
      for (int ni = 0; ni < 2; ++ni) {
        acc[mi][ni] = __builtin_amdgcn_mfma_f32_16x16x32_bf16(fah[mi], fbh[ni], acc[mi][ni], 0, 0, 0);
        acc[mi][ni] = __builtin_amdgcn_mfma_f32_16x16x32_bf16(fah[mi], fbl[ni], acc[mi][ni], 0, 0, 0);
        acc[mi][ni] = __builtin_amdgcn_mfma_f32_16x16x32_bf16(fal[mi], fbh[ni], acc[mi][ni], 0, 0, 0);
      }
  }
#pragma unroll
  for (int mi = 0; mi < 4; ++mi)
#pragma unroll
    for (int ni = 0; ni < 2; ++ni)
#pragma unroll
      for (int r = 0; r < 4; ++r) {
        int row = bm + wm * 64 + mi * 16 + l4 * 4 + r;
        int col = bn + wn * 32 + ni * 16 + l15;
        float v = acc[mi][ni][r];
        if (MODE == 1) v = (col < row) ? v * pc[((size_t)p * 256 + row) * 8 + 7] : 0.f;
        if (MODE == 2) v = (col <= row) ? v : 0.f;
        if (OUTK == 0)      C[(size_t)p * 65536 + (size_t)row * 256 + col] = v;
        else if (OUTK == 1) C[((size_t)(row * 32 + b)) * 256 + t * 128 + col] = v;
        else                C[((size_t)row * 64 + p) * 128 + col] = v;
      }
}

// ---------------------------------------------------------------------------
// Blocked triangular solve (I + L) delta = rw1 * v.  Grid 128 = (pair, chalf).
// ---------------------------------------------------------------------------
__global__ __launch_bounds__(256) void solve_kernel(
    const float* __restrict__ L,        // [64][256][256] strict-lower, rw1-scaled
    const u16* __restrict__ values,     // bf16 [8192][256]
    const float* __restrict__ pc,       // [64][256][8]
    float* __restrict__ delta) {        // [64][256][128]
  const int p = blockIdx.x >> 1, half = blockIdx.x & 1;
  const int b = p >> 1, t = p & 1;
  const int tid = threadIdx.x, w = tid >> 6, lane = tid & 63;
  __shared__ float ds[256][64];
  __shared__ float Ps[32][64];
  __shared__ float Db[32][33];
  const float* Lp = L + (size_t)p * 65536;

  for (int k = 0; k < 8; ++k) {
    const int s0 = k * 32;
    float acc[8];
#pragma unroll
    for (int i = 0; i < 8; ++i) {
      const int s = s0 + w * 8 + i;
      float rv = bf2f(values[((size_t)(s * 32 + b)) * 256 + t * 128 + half * 64 + lane]);
      acc[i] = rv * pc[((size_t)p * 256 + s) * 8 + 7];
    }
    const float* Lr0 = Lp + (size_t)(s0 + w * 8) * 256;
#pragma unroll 4
    for (int j = 0; j < s0; ++j) {
      float dj = ds[j][lane];
#pragma unroll
      for (int i = 0; i < 8; ++i) acc[i] -= Lr0[(size_t)i * 256 + j] * dj;
    }
    {
      const int r = tid >> 3, q0 = (tid & 7) * 4;
      float4 dv = *(const float4*)(Lp + (size_t)(s0 + r) * 256 + s0 + q0);
      Db[r][q0] = dv.x; Db[r][q0 + 1] = dv.y; Db[r][q0 + 2] = dv.z; Db[r][q0 + 3] = dv.w;
    }
#pragma unroll
    for (int i = 0; i < 8; ++i) Ps[w * 8 + i][lane] = acc[i];
    __syncthreads();
    if (w == 0) {
      float d[32];
#pragma unroll
      for (int r = 0; r < 32; ++r) {
        float xa = Ps[r][lane], xb = 0.f;
#pragma unroll
        for (int q = 0; q < 32; ++q) {
          if (q < r) {
            if (q & 1) xb -= Db[r][q] * d[q];
            else       xa -= Db[r][q] * d[q];
          }
        }
        float x = xa + xb;
        d[r] = x;
        ds[s0 + r][lane] = x;
        delta[((size_t)p * 256 + s0 + r) * 128 + half * 64 + lane] = x;
      }
    }
    __syncthreads();
  }
}

// ---------------------------------------------------------------------------
extern "C" void kernel_launch(void* const* d_in, const int* in_sizes, int n_in,
                              void* d_out, int out_size, void* d_ws, size_t ws_size,
                              hipStream_t stream) {
  const float* inputs = (const float*)d_in[0];
  const float* W_ih = (const float*)d_in[2];
  const float* W_hh = (const float*)d_in[3];
  const float* b_ih = (const float*)d_in[4];
  const float* b_hh = (const float*)d_in[5];
  const float* W_val = (const float*)d_in[6];
  const float* b_val = (const float*)d_in[7];
  const float* W_out = (const float*)d_in[8];
  const float* b_out = (const float*)d_in[9];

  float* out = (float*)d_out;
  float* out_tape = out + 2097152;
  float* out_rpos = out + 4194304;
  float* out_wpos = out + 4210688;

  char* ws = (char*)d_ws;
  float* posW      = (float*)(ws);                    // 16 MB  [64][256][256]
  float* posRs     = (float*)(ws + 16777216);         // 16 MB  (reused: reads_f32)
  float* LHm       = (float*)(ws + 33554432);         // 16 MB  (L, then Hm)
  u16*   values_bf = (u16*)  (ws + 50331648);         //  4 MB
  float* xg        = (float*)(ws + 54525952);         //  2 MB (dead after lstm)
  float* delta     = (float*)(ws + 54525952);         //  8 MB (aliases xg)
  float* pcb       = (float*)(ws + 62914560);         // 512 KB [64][256][8]
  float* hout      = (float*)(ws + 63438848);         // 512 KB [256][32][16]
  float* reads_f32 = posRs;

  // 1. values (bf16) = inputs @ W_val^T + b_val
  gemm_mfma<false, true><<<dim3(64, 4), 256, 0, stream>>>(inputs, W_val, b_val, values_bf, 256);
  // 2. xg (f32, permuted cols) = inputs @ W_ih^T + (b_ih + b_hh)
  gemm_nt<true><<<dim3(128, 1), 256, 0, stream>>>(inputs, W_ih, b_ih, b_hh, xg, 64);
  // 3. LSTM core -> raw h
  lstm_kernel<<<8, 64, 0, stream>>>(xg, W_hh, hout);
  // 3b. action heads -> packed coefficients pc
  head_kernel<<<512, 256, 0, stream>>>(hout, pcb);
  // 4. position trajectories
  pos_kernel<<<64, 64, 0, stream>>>(pcb, posW, posRs, out_rpos, out_wpos);
  // 5. L = rw1 (.) strict_tril(posW posW^T)
  bgemm<false, true, 1, 0, 256><<<dim3(4, 2, 64), 256, 0, stream>>>(
      posW, posW, pcb, LHm, 65536, 65536);
  // 6. blocked triangular solve -> delta
  solve_kernel<<<128, 256, 0, stream>>>(LHm, values_bf, pcb, delta);
  // 7. Hm = tril_incl(posRs posW^T)   (overwrites L)
  bgemm<false, true, 2, 0, 256><<<dim3(4, 2, 64), 256, 0, stream>>>(
      posRs, posW, pcb, LHm, 65536, 65536);
  // 8. reads = Hm @ delta   (reads layout [s*32+b][256])
  bgemm<false, false, 0, 1, 128><<<dim3(2, 2, 64), 256, 0, stream>>>(
      LHm, delta, pcb, reads_f32, 65536, 32768);
  // 9. out_tape = posW^T @ delta
  bgemm<true, false, 0, 2, 128><<<dim3(2, 2, 64), 256, 0, stream>>>(
      posW, delta, pcb, out_tape, 65536, 32768);
  // 10. outputs = reads @ W_out^T + b_out
  gemm_mfma<false, false><<<dim3(64, 4), 256, 0, stream>>>(reads_f32, W_out, b_out, out, 256);
}

// Round 7
// 442.569 us; speedup vs baseline: 1.6237x; 1.0246x over previous
//
#include <hip/hip_runtime.h>

#define SEQ    256
#define BATCH  32
#define NT     2
#define DIM    128
#define LTAPE  256

typedef float f32x4 __attribute__((ext_vector_type(4)));
typedef short s16x8 __attribute__((ext_vector_type(8)));
typedef unsigned int u32;
typedef unsigned short u16;

__device__ __forceinline__ float sigm(float x) { return 1.f / (1.f + __expf(-x)); }
__device__ __forceinline__ float tanh_(float x) { float e = __expf(2.f * x); return 1.f - 2.f / (e + 1.f); }
__device__ __forceinline__ u16 f2bf(float x) {
  u32 u = __builtin_bit_cast(u32, x);
  u32 r = (u + 0x7fffu + ((u >> 16) & 1u)) >> 16;
  return (u16)r;
}
__device__ __forceinline__ float bf2f(u16 b) {
  u32 u = ((u32)b) << 16; return __builtin_bit_cast(float, u);
}

// ---------------------------------------------------------------------------
// bf16 MFMA GEMM (verified): C[M][N] = A[M][256] @ W[N][256]^T + bias.
// ---------------------------------------------------------------------------
template<bool A_BF16, bool OUT_BF16>
__global__ __launch_bounds__(256) void gemm_mfma(
    const void* __restrict__ Av, const float* __restrict__ W,
    const float* __restrict__ bias, void* __restrict__ Cv, int N) {
  __shared__ u16 As[128 * 40];
  __shared__ u16 Bs[64 * 40];
  const int tid = threadIdx.x;
  const int bm = blockIdx.x * 128, bn = blockIdx.y * 64;
  const int wv = tid >> 6, lane = tid & 63;
  const int wm = wv >> 1, wn = wv & 1;
  const int l15 = lane & 15, l4 = lane >> 4;
  f32x4 acc[4][2] = {};
  const int arow = tid >> 1, ahalf = tid & 1;
  const int brow = (tid & 127) >> 1, bhalf = tid & 1;

  for (int k0 = 0; k0 < 256; k0 += 32) {
    u16 abuf[16];
    if (A_BF16) {
      const u16* A = (const u16*)Av;
      const uint4* p = (const uint4*)(A + (size_t)(bm + arow) * 256 + k0 + ahalf * 16);
      *(uint4*)(abuf) = p[0]; *(uint4*)(abuf + 8) = p[1];
    } else {
      const float* A = (const float*)Av;
      const float* src = A + (size_t)(bm + arow) * 256 + k0 + ahalf * 16;
      float4 x0 = ((const float4*)src)[0], x1 = ((const float4*)src)[1];
      float4 x2 = ((const float4*)src)[2], x3 = ((const float4*)src)[3];
      float xs[16] = {x0.x, x0.y, x0.z, x0.w, x1.x, x1.y, x1.z, x1.w,
                      x2.x, x2.y, x2.z, x2.w, x3.x, x3.y, x3.z, x3.w};
#pragma unroll
      for (int j = 0; j < 16; ++j) abuf[j] = f2bf(xs[j]);
    }
    u16 bbuf[16];
    if (tid < 128) {
      const float* src = W + (size_t)(bn + brow) * 256 + k0 + bhalf * 16;
      float4 x0 = ((const float4*)src)[0], x1 = ((const float4*)src)[1];
      float4 x2 = ((const float4*)src)[2], x3 = ((const float4*)src)[3];
      float xs[16] = {x0.x, x0.y, x0.z, x0.w, x1.x, x1.y, x1.z, x1.w,
                      x2.x, x2.y, x2.z, x2.w, x3.x, x3.y, x3.z, x3.w};
#pragma unroll
      for (int j = 0; j < 16; ++j) bbuf[j] = f2bf(xs[j]);
    }
    __syncthreads();
    *(uint4*)&As[arow * 40 + ahalf * 16] = *(const uint4*)(abuf);
    *(uint4*)&As[arow * 40 + ahalf * 16 + 8] = *(const uint4*)(abuf + 8);
    if (tid < 128) {
      *(uint4*)&Bs[brow * 40 + bhalf * 16] = *(const uint4*)(bbuf);
      *(uint4*)&Bs[brow * 40 + bhalf * 16 + 8] = *(const uint4*)(bbuf + 8);
    }
    __syncthreads();
    s16x8 af[4], bfr[2];
#pragma unroll
    for (int mi = 0; mi < 4; ++mi)
      af[mi] = *(const s16x8*)&As[(wm * 64 + mi * 16 + l15) * 40 + l4 * 8];
#pragma unroll
    for (int ni = 0; ni < 2; ++ni)
      bfr[ni] = *(const s16x8*)&Bs[(wn * 32 + ni * 16 + l15) * 40 + l4 * 8];
#pragma unroll
    for (int mi = 0; mi < 4; ++mi)
#pragma unroll
      for (int ni = 0; ni < 2; ++ni)
        acc[mi][ni] = __builtin_amdgcn_mfma_f32_16x16x32_bf16(af[mi], bfr[ni], acc[mi][ni], 0, 0, 0);
  }
#pragma unroll
  for (int mi = 0; mi < 4; ++mi)
#pragma unroll
    for (int ni = 0; ni < 2; ++ni)
#pragma unroll
      for (int r = 0; r < 4; ++r) {
        int row = bm + wm * 64 + mi * 16 + l4 * 4 + r;
        int col = bn + wn * 32 + ni * 16 + l15;
        float val = acc[mi][ni][r] + bias[col];
        if (OUT_BF16) ((u16*)Cv)[(size_t)row * N + col] = f2bf(val);
        else          ((float*)Cv)[(size_t)row * N + col] = val;
      }
}

// ---------------------------------------------------------------------------
// f32 SIMT GEMM for xg. PERM: output column n holds gate j=(n&3)*16+(n>>2).
// ---------------------------------------------------------------------------
template<bool PERM>
__global__ __launch_bounds__(256) void gemm_nt(
    const float* __restrict__ A, const float* __restrict__ W,
    const float* __restrict__ b1, const float* __restrict__ b2,
    float* __restrict__ C, int N) {
  __shared__ float Asm[16][68];
  __shared__ float Bsm[16][68];
  const int tid = threadIdx.x;
  const int bm = blockIdx.x * 64;
  const int bn = blockIdx.y * 64;
  const int lr = tid >> 2;
  const int lc4 = (tid & 3) * 4;
  const int tm = (tid & 15) * 4;
  const int tn = (tid >> 4) * 4;
  float acc[4][4];
#pragma unroll
  for (int i = 0; i < 4; ++i)
#pragma unroll
    for (int j = 0; j < 4; ++j) acc[i][j] = 0.f;
  int wr = bn + lr;
  if (PERM) wr = ((wr & 3) * 16) + (wr >> 2);
  for (int k0 = 0; k0 < 256; k0 += 16) {
    float4 av = *reinterpret_cast<const float4*>(&A[(bm + lr) * 256 + k0 + lc4]);
    float4 bv = *reinterpret_cast<const float4*>(&W[wr * 256 + k0 + lc4]);
    __syncthreads();
    Asm[lc4 + 0][lr] = av.x; Asm[lc4 + 1][lr] = av.y; Asm[lc4 + 2][lr] = av.z; Asm[lc4 + 3][lr] = av.w;
    Bsm[lc4 + 0][lr] = bv.x; Bsm[lc4 + 1][lr] = bv.y; Bsm[lc4 + 2][lr] = bv.z; Bsm[lc4 + 3][lr] = bv.w;
    __syncthreads();
#pragma unroll
    for (int kk = 0; kk < 16; ++kk) {
      float4 a = *reinterpret_cast<const float4*>(&Asm[kk][tm]);
      float4 b = *reinterpret_cast<const float4*>(&Bsm[kk][tn]);
      float a_[4] = {a.x, a.y, a.z, a.w};
      float b_[4] = {b.x, b.y, b.z, b.w};
#pragma unroll
      for (int i = 0; i < 4; ++i)
#pragma unroll
        for (int j = 0; j < 4; ++j) acc[i][j] += a_[i] * b_[j];
    }
  }
#pragma unroll
  for (int i = 0; i < 4; ++i)
#pragma unroll
    for (int j = 0; j < 4; ++j) {
      int n = bn + tn + j;
      int jm = PERM ? ((n & 3) * 16) + (n >> 2) : n;
      float bias = b1[jm] + (b2 ? b2[jm] : 0.f);
      C[(size_t)(bm + tm + i) * N + n] = acc[i][j] + bias;
    }
}

// ---------------------------------------------------------------------------
// LSTM core. 8 blocks x 64; lane = b4*16 + k owns h,c of unit k for batch
// blockIdx*4+b4 and all 4 gate rows of W_hh in registers (64 VGPRs).
// __launch_bounds__(64, 1): min 1 wave/EU -> full VGPR budget; without it the
// backend capped at 64 VGPRs and rematerialized W_hh loads inside the loop
// (r6: VGPR_Count=64, 1027 cyc/step). Matvec tree-reduced (4 partials/gate).
// ---------------------------------------------------------------------------
__global__ __launch_bounds__(64, 1) void lstm_kernel(
    const float* __restrict__ xg,    // [SEQ][32][64] permuted n=k*4+q
    const float* __restrict__ W_hh,  // [64][16]
    float* __restrict__ hout) {      // [SEQ][32][16]
  const int lane = threadIdx.x;
  const int b4 = lane >> 4, k = lane & 15;
  const int b = blockIdx.x * 4 + b4;
  const int lbase = lane & 48;
  float w[4][16];
#pragma unroll
  for (int q = 0; q < 4; ++q)
#pragma unroll
    for (int kk = 0; kk < 16; ++kk)
      w[q][kk] = W_hh[(q * 16 + k) * 16 + kk];
  float h = 0.f, c = 0.f;
  const float* xb = xg + (size_t)b * 64 + k * 4;
  float4 xA = *(const float4*)(xb + (size_t)0 * 2048);
  float4 xB = *(const float4*)(xb + (size_t)1 * 2048);
  float4 xC = *(const float4*)(xb + (size_t)2 * 2048);
  float4 xD = *(const float4*)(xb + (size_t)3 * 2048);

#define LSTM_STEP(S, XV)                                                     \
  {                                                                          \
    float hb[16];                                                            \
    _Pragma("unroll") for (int kk = 0; kk < 16; ++kk)                        \
      hb[kk] = __shfl(h, lbase + kk, 64);                                    \
    float g0, g1, g2, g3;                                                    \
    _Pragma("unroll") for (int q = 0; q < 4; ++q) {                          \
      float pa = w[q][0] * hb[0], pb = w[q][1] * hb[1];                      \
      float pc_ = w[q][2] * hb[2], pd = w[q][3] * hb[3];                     \
      _Pragma("unroll") for (int kk = 4; kk < 16; kk += 4) {                 \
        pa += w[q][kk + 0] * hb[kk + 0];                                     \
        pb += w[q][kk + 1] * hb[kk + 1];                                     \
        pc_ += w[q][kk + 2] * hb[kk + 2];                                    \
        pd += w[q][kk + 3] * hb[kk + 3];                                     \
      }                                                                      \
      float r = (pa + pb) + (pc_ + pd);                                      \
      if (q == 0) g0 = XV.x + r;                                             \
      else if (q == 1) g1 = XV.y + r;                                        \
      else if (q == 2) g2 = XV.z + r;                                        \
      else g3 = XV.w + r;                                                    \
    }                                                                        \
    c = sigm(g1) * c + sigm(g0) * tanh_(g2);                                 \
    h = sigm(g3) * tanh_(c);                                                 \
    hout[(size_t)((S) * 32 + b) * 16 + k] = h;                               \
  }

  for (int s0 = 0; s0 < SEQ; s0 += 4) {
    int p4 = s0 + 4; if (p4 > 255) p4 = 255;
    int p5 = s0 + 5; if (p5 > 255) p5 = 255;
    int p6 = s0 + 6; if (p6 > 255) p6 = 255;
    int p7 = s0 + 7; if (p7 > 255) p7 = 255;
    float4 nA = *(const float4*)(xb + (size_t)p4 * 2048);
    float4 nB = *(const float4*)(xb + (size_t)p5 * 2048);
    float4 nC = *(const float4*)(xb + (size_t)p6 * 2048);
    float4 nD = *(const float4*)(xb + (size_t)p7 * 2048);
    LSTM_STEP(s0 + 0, xA);
    LSTM_STEP(s0 + 1, xB);
    LSTM_STEP(s0 + 2, xC);
    LSTM_STEP(s0 + 3, xD);
    xA = nA; xB = nB; xC = nC; xD = nD;
  }
#undef LSTM_STEP
}

// ---------------------------------------------------------------------------
// Action heads: softmax/sigmoid from raw h -> pc[p][s][8] =
// {rd0,rd1,rd2,wd0,wd1,wd2,rw0,rw1}. idx == p*2048 + s*8 + e.
// ---------------------------------------------------------------------------
__global__ __launch_bounds__(256) void head_kernel(
    const float* __restrict__ hout,  // [SEQ][32][16]
    float* __restrict__ pc) {        // [64][256][8]
  const int idx = blockIdx.x * 256 + threadIdx.x;
  const int e = idx & 7, s = (idx >> 3) & 255, p = idx >> 11;
  const int b = p >> 1, t = p & 1;
  const float* hp = hout + ((size_t)(s * 32 + b)) * 16 + t * 8;
  float outv;
  if (e < 3) {
    float a0 = hp[0], a1 = hp[1], a2 = hp[2];
    float m = fmaxf(a0, fmaxf(a1, a2));
    float e0 = __expf(a0 - m), e1 = __expf(a1 - m), e2 = __expf(a2 - m);
    float inv = 1.f / (e0 + e1 + e2);
    outv = (e == 0 ? e0 : (e == 1 ? e1 : e2)) * inv;
  } else if (e < 6) {
    float a3 = hp[3], a4 = hp[4], a5 = hp[5];
    float m = fmaxf(a3, fmaxf(a4, a5));
    float e0 = __expf(a3 - m), e1 = __expf(a4 - m), e2 = __expf(a5 - m);
    float inv = 1.f / (e0 + e1 + e2);
    outv = (e == 3 ? e0 : (e == 4 ? e1 : e2)) * inv;
  } else {
    outv = sigm(hp[e]);
  }
  pc[idx] = outv;
}

// ---------------------------------------------------------------------------
// Position precompute, 4x unrolled with 4-step coefficient prefetch from pc.
// ---------------------------------------------------------------------------
__global__ __launch_bounds__(64, 1) void pos_kernel(
    const float* __restrict__ pc,      // [64][256][8]
    float* __restrict__ posW, float* __restrict__ posRs,
    float* __restrict__ out_rpos, float* __restrict__ out_wpos) {
  const int p = blockIdx.x, lane = threadIdx.x;
  float r0 = 0, r1 = 0, r2 = 0, r3 = 0, w0 = 0, w1 = 0, w2 = 0, w3 = 0;
  if (lane == 0) { r0 = 1.f; w0 = 1.f; }
  const float* pcb = pc + (size_t)p * 2048;
  float4 c0 = *(const float4*)&pcb[0];
  float4 c1 = *(const float4*)&pcb[4];
  for (int s0 = 0; s0 < SEQ; s0 += 4) {
    float4 pf[8];
#pragma unroll
    for (int u = 0; u < 4; ++u) {
      int sn = s0 + u + 1; if (sn > 255) sn = 255;
      pf[2 * u]     = *(const float4*)&pcb[sn * 8];
      pf[2 * u + 1] = *(const float4*)&pcb[sn * 8 + 4];
    }
#pragma unroll
    for (int u = 0; u < 4; ++u) {
      const int s = s0 + u;
      size_t ob = ((size_t)p * 256 + s) * 256 + lane * 4;
      *(float4*)(posW + ob) = make_float4(w0, w1, w2, w3);
      float rw0 = c1.z;
      *(float4*)(posRs + ob) = make_float4(r0 * rw0, r1 * rw0, r2 * rw0, r3 * rw0);
      const float crd0 = c0.x, crd1 = c0.y, crd2 = c0.z;
      const float cwd0 = c0.w, cwd1 = c1.x, cwd2 = c1.y;
      float rn  = __shfl(r0, (lane + 1) & 63, 64);
      float rpv = __shfl(r3, (lane + 63) & 63, 64);
      float nw0 = r1 * cwd0 + w0 * cwd1 + rpv * cwd2;
      float nr0 = r1 * crd0 + r0 * crd1 + rpv * crd2;
      float nw1 = r2 * cwd0 + w1 * cwd1 + r0 * cwd2;
      float nr1 = r2 * crd0 + r1 * crd1 + r0 * crd2;
      float nw2 = r3 * cwd0 + w2 * cwd1 + r1 * cwd2;
      float nr2 = r3 * crd0 + r2 * crd1 + r1 * crd2;
      float nw3 = rn * cwd0 + w3 * cwd1 + r2 * cwd2;
      float nr3 = rn * crd0 + r3 * crd1 + r2 * crd2;
      r0 = nr0; r1 = nr1; r2 = nr2; r3 = nr3;
      w0 = nw0; w1 = nw1; w2 = nw2; w3 = nw3;
      c0 = pf[2 * u]; c1 = pf[2 * u + 1];
    }
  }
  out_rpos[(size_t)(lane * 4 + 0) * 64 + p] = r0;
  out_rpos[(size_t)(lane * 4 + 1) * 64 + p] = r1;
  out_rpos[(size_t)(lane * 4 + 2) * 64 + p] = r2;
  out_rpos[(size_t)(lane * 4 + 3) * 64 + p] = r3;
  out_wpos[(size_t)(lane * 4 + 0) * 64 + p] = w0;
  out_wpos[(size_t)(lane * 4 + 1) * 64 + p] = w1;
  out_wpos[(size_t)(lane * 4 + 2) * 64 + p] = w2;
  out_wpos[(size_t)(lane * 4 + 3) * 64 + p] = w3;
}

// ---------------------------------------------------------------------------
// Batched per-pair GEMM with hi/lo bf16 compensation (3 MFMA terms ~ f32).
// MODE: 0 plain, 1 strict-lower x rw1[row] (skips all-upper tiles),
//       2 lower-incl (zero-fills all-upper tiles without compute).
// ---------------------------------------------------------------------------
template<bool TRANS_A, bool B_NT, int MODE, int OUTK, int BROW>
__global__ __launch_bounds__(256) void bgemm(
    const float* __restrict__ A, const float* __restrict__ B,
    const float* __restrict__ pc, float* __restrict__ C,
    size_t sA, size_t sB) {
  __shared__ u16 Ah[128 * 40], Al[128 * 40], Bh[64 * 40], Bl[64 * 40];
  const int p = blockIdx.z;
  const int bm = blockIdx.y * 128, bn = blockIdx.x * 64;
  const int tid = threadIdx.x, wv = tid >> 6, lane = tid & 63;
  const int wm = wv >> 1, wn = wv & 1, l15 = lane & 15, l4 = lane >> 4;
  const int b = p >> 1, t = p & 1;

  if (MODE == 1 && bn >= bm + 128) return;
  if (MODE == 2 && bn >= bm + 128) {
#pragma unroll
    for (int mi = 0; mi < 4; ++mi)
#pragma unroll
      for (int ni = 0; ni < 2; ++ni)
#pragma unroll
        for (int r = 0; r < 4; ++r) {
          int row = bm + wm * 64 + mi * 16 + l4 * 4 + r;
          int col = bn + wn * 32 + ni * 16 + l15;
          C[(size_t)p * 65536 + (size_t)row * 256 + col] = 0.f;
        }
    return;
  }

  const float* Ap = A + (size_t)p * sA;
  const float* Bp = B + (size_t)p * sB;
  f32x4 acc[4][2] = {};

  for (int k0 = 0; k0 < 256; k0 += 32) {
    float xa[16];
    if (!TRANS_A) {
      const int m = tid >> 1, kq = (tid & 1) * 16;
      const float* src = Ap + (size_t)(bm + m) * 256 + k0 + kq;
#pragma unroll
      for (int j = 0; j < 4; ++j) *(float4*)(xa + j * 4) = ((const float4*)src)[j];
    } else {
      const int kr = tid >> 3, mq = (tid & 7) * 16;
      const float* src = Ap + (size_t)(k0 + kr) * 256 + bm + mq;
#pragma unroll
      for (int j = 0; j < 4; ++j) *(float4*)(xa + j * 4) = ((const float4*)src)[j];
    }
    u16 ah[16], al[16];
#pragma unroll
    for (int j = 0; j < 16; ++j) {
      u16 hh = f2bf(xa[j]);
      ah[j] = hh; al[j] = f2bf(xa[j] - bf2f(hh));
    }
    float xb[8];
    if (B_NT) {
      const int n = tid >> 2, kq = (tid & 3) * 8;
      const float* src = Bp + (size_t)(bn + n) * 256 + k0 + kq;
      *(float4*)(xb) = ((const float4*)src)[0];
      *(float4*)(xb + 4) = ((const float4*)src)[1];
    } else {
      const int kr = tid >> 3, nq = (tid & 7) * 8;
      const float* src = Bp + (size_t)(k0 + kr) * BROW + bn + nq;
      *(float4*)(xb) = ((const float4*)src)[0];
      *(float4*)(xb + 4) = ((const float4*)src)[1];
    }
    u16 bh[8], bl[8];
#pragma unroll
    for (int j = 0; j < 8; ++j) {
      u16 hh = f2bf(xb[j]);
      bh[j] = hh; bl[j] = f2bf(xb[j] - bf2f(hh));
    }
    __syncthreads();
    if (!TRANS_A) {
      const int m = tid >> 1, kq = (tid & 1) * 16;
      *(uint4*)&Ah[m * 40 + kq]     = *(const uint4*)(ah);
      *(uint4*)&Ah[m * 40 + kq + 8] = *(const uint4*)(ah + 8);
      *(uint4*)&Al[m * 40 + kq]     = *(const uint4*)(al);
      *(uint4*)&Al[m * 40 + kq + 8] = *(const uint4*)(al + 8);
    } else {
      const int kr = tid >> 3, mq = (tid & 7) * 16;
#pragma unroll
      for (int j = 0; j < 16; ++j) {
        Ah[(mq + j) * 40 + kr] = ah[j];
        Al[(mq + j) * 40 + kr] = al[j];
      }
    }
    if (B_NT) {
      const int n = tid >> 2, kq = (tid & 3) * 8;
      *(uint4*)&Bh[n * 40 + kq] = *(const uint4*)(bh);
      *(uint4*)&Bl[n * 40 + kq] = *(const uint4*)(bl);
    } else {
      const int kr = tid >> 3, nq = (tid & 7) * 8;
#pragma unroll
      for (int j = 0; j < 8; ++j) {
        Bh[(nq + j) * 40 + kr] = bh[j];
        Bl[(nq + j) * 40 + kr] = bl[j];
      }
    }
    __syncthreads();
    s16x8 fah[4], fal[4], fbh[2], fbl[2];
#pragma unroll
    for (int mi = 0; mi < 4; ++mi) {
      fah[mi] = *(const s16x8*)&Ah[(wm * 64 + mi * 16 + l15) * 40 + l4 * 8];
      fal[mi] = *(const s16x8*)&Al[(wm * 64 + mi * 16 + l15) * 40 + l4 * 8];
    }
#pragma unroll
    for (int ni = 0; ni < 2; ++ni) {
      fbh[ni] = *(const s16x8*)&Bh[(wn * 32 + ni * 16 + l15) * 40 + l4 * 8];
      fbl[ni] = *(const s16x8*)&Bl[(wn * 32 + ni * 16 + l15) * 40 + l4 * 8];
    }
#pragma unroll
    for (int mi = 0; mi < 4; ++mi)
#pragma unroll
      for (int ni = 0; ni < 2; ++ni) {
        acc[mi][ni] = __builtin_amdgcn_mfma_f32_16x16x32_bf16(fah[mi], fbh[ni], acc[mi][ni], 0, 0, 0);
        acc[mi][ni] = __builtin_amdgcn_mfma_f32_16x16x32_bf16(fah[mi], fbl[ni], acc[mi][ni], 0, 0, 0);
        acc[mi][ni] = __builtin_amdgcn_mfma_f32_16x16x32_bf16(fal[mi], fbh[ni], acc[mi][ni], 0, 0, 0);
      }
  }
#pragma unroll
  for (int mi = 0; mi < 4; ++mi)
#pragma unroll
    for (int ni = 0; ni < 2; ++ni)
#pragma unroll
      for (int r = 0; r < 4; ++r) {
        int row = bm + wm * 64 + mi * 16 + l4 * 4 + r;
        int col = bn + wn * 32 + ni * 16 + l15;
        float v = acc[mi][ni][r];
        if (MODE == 1) v = (col < row) ? v * pc[((size_t)p * 256 + row) * 8 + 7] : 0.f;
        if (MODE == 2) v = (col <= row) ? v : 0.f;
        if (OUTK == 0)      C[(size_t)p * 65536 + (size_t)row * 256 + col] = v;
        else if (OUTK == 1) C[((size_t)(row * 32 + b)) * 256 + t * 128 + col] = v;
        else                C[((size_t)row * 64 + p) * 128 + col] = v;
      }
}

// ---------------------------------------------------------------------------
// Blocked triangular solve (I + L) delta = rw1 * v.  Grid 128 = (pair, chalf).
// ---------------------------------------------------------------------------
__global__ __launch_bounds__(256) void solve_kernel(
    const float* __restrict__ L,        // [64][256][256] strict-lower, rw1-scaled
    const u16* __restrict__ values,     // bf16 [8192][256]
    const float* __restrict__ pc,       // [64][256][8]
    float* __restrict__ delta) {        // [64][256][128]
  const int p = blockIdx.x >> 1, half = blockIdx.x & 1;
  const int b = p >> 1, t = p & 1;
  const int tid = threadIdx.x, w = tid >> 6, lane = tid & 63;
  __shared__ float ds[256][64];
  __shared__ float Ps[32][64];
  __shared__ float Db[32][33];
  const float* Lp = L + (size_t)p * 65536;

  for (int k = 0; k < 8; ++k) {
    const int s0 = k * 32;
    float acc[8];
#pragma unroll
    for (int i = 0; i < 8; ++i) {
      const int s = s0 + w * 8 + i;
      float rv = bf2f(values[((size_t)(s * 32 + b)) * 256 + t * 128 + half * 64 + lane]);
      acc[i] = rv * pc[((size_t)p * 256 + s) * 8 + 7];
    }
    const float* Lr0 = Lp + (size_t)(s0 + w * 8) * 256;
#pragma unroll 4
    for (int j = 0; j < s0; ++j) {
      float dj = ds[j][lane];
#pragma unroll
      for (int i = 0; i < 8; ++i) acc[i] -= Lr0[(size_t)i * 256 + j] * dj;
    }
    {
      const int r = tid >> 3, q0 = (tid & 7) * 4;
      float4 dv = *(const float4*)(Lp + (size_t)(s0 + r) * 256 + s0 + q0);
      Db[r][q0] = dv.x; Db[r][q0 + 1] = dv.y; Db[r][q0 + 2] = dv.z; Db[r][q0 + 3] = dv.w;
    }
#pragma unroll
    for (int i = 0; i < 8; ++i) Ps[w * 8 + i][lane] = acc[i];
    __syncthreads();
    if (w == 0) {
      float d[32];
#pragma unroll
      for (int r = 0; r < 32; ++r) {
        float xa = Ps[r][lane], xb = 0.f;
#pragma unroll
        for (int q = 0; q < 32; ++q) {
          if (q < r) {
            if (q & 1) xb -= Db[r][q] * d[q];
            else       xa -= Db[r][q] * d[q];
          }
        }
        float x = xa + xb;
        d[r] = x;
        ds[s0 + r][lane] = x;
        delta[((size_t)p * 256 + s0 + r) * 128 + half * 64 + lane] = x;
      }
    }
    __syncthreads();
  }
}

// ---------------------------------------------------------------------------
extern "C" void kernel_launch(void* const* d_in, const int* in_sizes, int n_in,
                              void* d_out, int out_size, void* d_ws, size_t ws_size,
                              hipStream_t stream) {
  const float* inputs = (const float*)d_in[0];
  const float* W_ih = (const float*)d_in[2];
  const float* W_hh = (const float*)d_in[3];
  const float* b_ih = (const float*)d_in[4];
  const float* b_hh = (const float*)d_in[5];
  const float* W_val = (const float*)d_in[6];
  const float* b_val = (const float*)d_in[7];
  const float* W_out = (const float*)d_in[8];
  const float* b_out = (const float*)d_in[9];

  float* out = (float*)d_out;
  float* out_tape = out + 2097152;
  float* out_rpos = out + 4194304;
  float* out_wpos = out + 4210688;

  char* ws = (char*)d_ws;
  float* posW      = (float*)(ws);                    // 16 MB  [64][256][256]
  float* posRs     = (float*)(ws + 16777216);         // 16 MB  (reused: reads_f32)
  float* LHm       = (float*)(ws + 33554432);         // 16 MB  (L, then Hm)
  u16*   values_bf = (u16*)  (ws + 50331648);         //  4 MB
  float* xg        = (float*)(ws + 54525952);         //  2 MB (dead after lstm)
  float* delta     = (float*)(ws + 54525952);         //  8 MB (aliases xg)
  float* pcb       = (float*)(ws + 62914560);         // 512 KB [64][256][8]
  float* hout      = (float*)(ws + 63438848);         // 512 KB [256][32][16]
  float* reads_f32 = posRs;

  // 1. values (bf16) = inputs @ W_val^T + b_val
  gemm_mfma<false, true><<<dim3(64, 4), 256, 0, stream>>>(inputs, W_val, b_val, values_bf, 256);
  // 2. xg (f32, permuted cols) = inputs @ W_ih^T + (b_ih + b_hh)
  gemm_nt<true><<<dim3(128, 1), 256, 0, stream>>>(inputs, W_ih, b_ih, b_hh, xg, 64);
  // 3. LSTM core -> raw h
  lstm_kernel<<<8, 64, 0, stream>>>(xg, W_hh, hout);
  // 3b. action heads -> packed coefficients pc
  head_kernel<<<512, 256, 0, stream>>>(hout, pcb);
  // 4. position trajectories
  pos_kernel<<<64, 64, 0, stream>>>(pcb, posW, posRs, out_rpos, out_wpos);
  // 5. L = rw1 (.) strict_tril(posW posW^T)
  bgemm<false, true, 1, 0, 256><<<dim3(4, 2, 64), 256, 0, stream>>>(
      posW, posW, pcb, LHm, 65536, 65536);
  // 6. blocked triangular solve -> delta
  solve_kernel<<<128, 256, 0, stream>>>(LHm, values_bf, pcb, delta);
  // 7. Hm = tril_incl(posRs posW^T)   (overwrites L)
  bgemm<false, true, 2, 0, 256><<<dim3(4, 2, 64), 256, 0, stream>>>(
      posRs, posW, pcb, LHm, 65536, 65536);
  // 8. reads = Hm @ delta   (reads layout [s*32+b][256])
  bgemm<false, false, 0, 1, 128><<<dim3(2, 2, 64), 256, 0, stream>>>(
      LHm, delta, pcb, reads_f32, 65536, 32768);
  // 9. out_tape = posW^T @ delta
  bgemm<true, false, 0, 2, 128><<<dim3(2, 2, 64), 256, 0, stream>>>(
      posW, delta, pcb, out_tape, 65536, 32768);
  // 10. outputs = reads @ W_out^T + b_out
  gemm_mfma<false, false><<<dim3(64, 4), 256, 0, stream>>>(reads_f32, W_out, b_out, out, 256);
}

// Round 8
// 441.069 us; speedup vs baseline: 1.6293x; 1.0034x over previous
//
#include <hip/hip_runtime.h>

#define SEQ    256
#define BATCH  32
#define NT     2
#define DIM    128
#define LTAPE  256

typedef float f32x4 __attribute__((ext_vector_type(4)));
typedef short s16x8 __attribute__((ext_vector_type(8)));
typedef unsigned int u32;
typedef unsigned short u16;

__device__ __forceinline__ float sigm(float x) { return 1.f / (1.f + __expf(-x)); }
__device__ __forceinline__ float tanh_(float x) { float e = __expf(2.f * x); return 1.f - 2.f / (e + 1.f); }
__device__ __forceinline__ u16 f2bf(float x) {
  u32 u = __builtin_bit_cast(u32, x);
  u32 r = (u + 0x7fffu + ((u >> 16) & 1u)) >> 16;
  return (u16)r;
}
__device__ __forceinline__ float bf2f(u16 b) {
  u32 u = ((u32)b) << 16; return __builtin_bit_cast(float, u);
}

// ---------------------------------------------------------------------------
// bf16 MFMA GEMM (verified): C[M][N] = A[M][256] @ W[N][256]^T + bias.
// ---------------------------------------------------------------------------
template<bool A_BF16, bool OUT_BF16>
__global__ __launch_bounds__(256) void gemm_mfma(
    const void* __restrict__ Av, const float* __restrict__ W,
    const float* __restrict__ bias, void* __restrict__ Cv, int N) {
  __shared__ u16 As[128 * 40];
  __shared__ u16 Bs[64 * 40];
  const int tid = threadIdx.x;
  const int bm = blockIdx.x * 128, bn = blockIdx.y * 64;
  const int wv = tid >> 6, lane = tid & 63;
  const int wm = wv >> 1, wn = wv & 1;
  const int l15 = lane & 15, l4 = lane >> 4;
  f32x4 acc[4][2] = {};
  const int arow = tid >> 1, ahalf = tid & 1;
  const int brow = (tid & 127) >> 1, bhalf = tid & 1;

  for (int k0 = 0; k0 < 256; k0 += 32) {
    u16 abuf[16];
    if (A_BF16) {
      const u16* A = (const u16*)Av;
      const uint4* p = (const uint4*)(A + (size_t)(bm + arow) * 256 + k0 + ahalf * 16);
      *(uint4*)(abuf) = p[0]; *(uint4*)(abuf + 8) = p[1];
    } else {
      const float* A = (const float*)Av;
      const float* src = A + (size_t)(bm + arow) * 256 + k0 + ahalf * 16;
      float4 x0 = ((const float4*)src)[0], x1 = ((const float4*)src)[1];
      float4 x2 = ((const float4*)src)[2], x3 = ((const float4*)src)[3];
      float xs[16] = {x0.x, x0.y, x0.z, x0.w, x1.x, x1.y, x1.z, x1.w,
                      x2.x, x2.y, x2.z, x2.w, x3.x, x3.y, x3.z, x3.w};
#pragma unroll
      for (int j = 0; j < 16; ++j) abuf[j] = f2bf(xs[j]);
    }
    u16 bbuf[16];
    if (tid < 128) {
      const float* src = W + (size_t)(bn + brow) * 256 + k0 + bhalf * 16;
      float4 x0 = ((const float4*)src)[0], x1 = ((const float4*)src)[1];
      float4 x2 = ((const float4*)src)[2], x3 = ((const float4*)src)[3];
      float xs[16] = {x0.x, x0.y, x0.z, x0.w, x1.x, x1.y, x1.z, x1.w,
                      x2.x, x2.y, x2.z, x2.w, x3.x, x3.y, x3.z, x3.w};
#pragma unroll
      for (int j = 0; j < 16; ++j) bbuf[j] = f2bf(xs[j]);
    }
    __syncthreads();
    *(uint4*)&As[arow * 40 + ahalf * 16] = *(const uint4*)(abuf);
    *(uint4*)&As[arow * 40 + ahalf * 16 + 8] = *(const uint4*)(abuf + 8);
    if (tid < 128) {
      *(uint4*)&Bs[brow * 40 + bhalf * 16] = *(const uint4*)(bbuf);
      *(uint4*)&Bs[brow * 40 + bhalf * 16 + 8] = *(const uint4*)(bbuf + 8);
    }
    __syncthreads();
    s16x8 af[4], bfr[2];
#pragma unroll
    for (int mi = 0; mi < 4; ++mi)
      af[mi] = *(const s16x8*)&As[(wm * 64 + mi * 16 + l15) * 40 + l4 * 8];
#pragma unroll
    for (int ni = 0; ni < 2; ++ni)
      bfr[ni] = *(const s16x8*)&Bs[(wn * 32 + ni * 16 + l15) * 40 + l4 * 8];
#pragma unroll
    for (int mi = 0; mi < 4; ++mi)
#pragma unroll
      for (int ni = 0; ni < 2; ++ni)
        acc[mi][ni] = __builtin_amdgcn_mfma_f32_16x16x32_bf16(af[mi], bfr[ni], acc[mi][ni], 0, 0, 0);
  }
#pragma unroll
  for (int mi = 0; mi < 4; ++mi)
#pragma unroll
    for (int ni = 0; ni < 2; ++ni)
#pragma unroll
      for (int r = 0; r < 4; ++r) {
        int row = bm + wm * 64 + mi * 16 + l4 * 4 + r;
        int col = bn + wn * 32 + ni * 16 + l15;
        float val = acc[mi][ni][r] + bias[col];
        if (OUT_BF16) ((u16*)Cv)[(size_t)row * N + col] = f2bf(val);
        else          ((float*)Cv)[(size_t)row * N + col] = val;
      }
}

// ---------------------------------------------------------------------------
// f32 SIMT GEMM for xg (original torch gate-order columns).
// ---------------------------------------------------------------------------
__global__ __launch_bounds__(256) void gemm_nt(
    const float* __restrict__ A, const float* __restrict__ W,
    const float* __restrict__ b1, const float* __restrict__ b2,
    float* __restrict__ C, int N) {
  __shared__ float Asm[16][68];
  __shared__ float Bsm[16][68];
  const int tid = threadIdx.x;
  const int bm = blockIdx.x * 64;
  const int bn = blockIdx.y * 64;
  const int lr = tid >> 2;
  const int lc4 = (tid & 3) * 4;
  const int tm = (tid & 15) * 4;
  const int tn = (tid >> 4) * 4;
  float acc[4][4];
#pragma unroll
  for (int i = 0; i < 4; ++i)
#pragma unroll
    for (int j = 0; j < 4; ++j) acc[i][j] = 0.f;
  for (int k0 = 0; k0 < 256; k0 += 16) {
    float4 av = *reinterpret_cast<const float4*>(&A[(bm + lr) * 256 + k0 + lc4]);
    float4 bv = *reinterpret_cast<const float4*>(&W[(bn + lr) * 256 + k0 + lc4]);
    __syncthreads();
    Asm[lc4 + 0][lr] = av.x; Asm[lc4 + 1][lr] = av.y; Asm[lc4 + 2][lr] = av.z; Asm[lc4 + 3][lr] = av.w;
    Bsm[lc4 + 0][lr] = bv.x; Bsm[lc4 + 1][lr] = bv.y; Bsm[lc4 + 2][lr] = bv.z; Bsm[lc4 + 3][lr] = bv.w;
    __syncthreads();
#pragma unroll
    for (int kk = 0; kk < 16; ++kk) {
      float4 a = *reinterpret_cast<const float4*>(&Asm[kk][tm]);
      float4 b = *reinterpret_cast<const float4*>(&Bsm[kk][tn]);
      float a_[4] = {a.x, a.y, a.z, a.w};
      float b_[4] = {b.x, b.y, b.z, b.w};
#pragma unroll
      for (int i = 0; i < 4; ++i)
#pragma unroll
        for (int j = 0; j < 4; ++j) acc[i][j] += a_[i] * b_[j];
    }
  }
#pragma unroll
  for (int i = 0; i < 4; ++i)
#pragma unroll
    for (int j = 0; j < 4; ++j) {
      int n = bn + tn + j;
      float bias = b1[n] + (b2 ? b2[n] : 0.f);
      C[(size_t)(bm + tm + i) * N + n] = acc[i][j] + bias;
    }
}

// ---------------------------------------------------------------------------
// LSTM core, round-1 topology: 32 blocks (1 batch/wave); lane = q*16+k owns
// ONE W_hh row (16 regs -- small enough that LLVM keeps it resident; the
// r6/r7 4-row variant had 64 regs/lane and the compiler sank the loads into
// the loop, ~930 cyc/step). Per step: 16-FMA tree + 4-shfl gate gather +
// c,h + 16-shfl broadcast. xg prefetched 4 deep; heads deferred.
// ---------------------------------------------------------------------------
__global__ __launch_bounds__(64, 1) void lstm_kernel(
    const float* __restrict__ xg,    // [SEQ][32][64] torch gate order
    const float* __restrict__ W_hh,  // [64][16]
    float* __restrict__ hout) {      // [SEQ][32][16]
  const int lane = threadIdx.x;
  const int b = blockIdx.x;
  const int k = lane & 15, q = lane >> 4;
  float w[16];
#pragma unroll
  for (int kk = 0; kk < 16; ++kk) w[kk] = W_hh[lane * 16 + kk];
  float h = 0.f, c = 0.f;
  const float* xb = xg + (size_t)b * 64 + lane;
  float xA = xb[0 * 2048];
  float xB = xb[1 * 2048];
  float xC = xb[2 * 2048];
  float xD = xb[3 * 2048];

#define LSTM_STEP(S, XV)                                                     \
  {                                                                          \
    float hb[16];                                                            \
    _Pragma("unroll") for (int kk = 0; kk < 16; ++kk)                        \
      hb[kk] = __shfl(h, kk, 64);                                            \
    float pa = w[0] * hb[0], pb = w[1] * hb[1];                              \
    float pcc = w[2] * hb[2], pd = w[3] * hb[3];                             \
    _Pragma("unroll") for (int kk = 4; kk < 16; kk += 4) {                   \
      pa += w[kk + 0] * hb[kk + 0];                                         \
      pb += w[kk + 1] * hb[kk + 1];                                         \
      pcc += w[kk + 2] * hb[kk + 2];                                        \
      pd += w[kk + 3] * hb[kk + 3];                                         \
    }                                                                        \
    float g = XV + (pa + pb) + (pcc + pd);                                   \
    float gi = __shfl(g, k, 64);                                             \
    float gf = __shfl(g, 16 + k, 64);                                        \
    float gg = __shfl(g, 32 + k, 64);                                        \
    float go = __shfl(g, 48 + k, 64);                                        \
    c = sigm(gf) * c + sigm(gi) * tanh_(gg);                                 \
    h = sigm(go) * tanh_(c);                                                 \
    if (q == 0) hout[(size_t)((S) * 32 + b) * 16 + k] = h;                   \
  }

  for (int s0 = 0; s0 < SEQ; s0 += 4) {
    int p4 = s0 + 4; if (p4 > 255) p4 = 255;
    int p5 = s0 + 5; if (p5 > 255) p5 = 255;
    int p6 = s0 + 6; if (p6 > 255) p6 = 255;
    int p7 = s0 + 7; if (p7 > 255) p7 = 255;
    float nA = xb[(size_t)p4 * 2048];
    float nB = xb[(size_t)p5 * 2048];
    float nC = xb[(size_t)p6 * 2048];
    float nD = xb[(size_t)p7 * 2048];
    LSTM_STEP(s0 + 0, xA);
    LSTM_STEP(s0 + 1, xB);
    LSTM_STEP(s0 + 2, xC);
    LSTM_STEP(s0 + 3, xD);
    xA = nA; xB = nB; xC = nC; xD = nD;
  }
#undef LSTM_STEP
}

// ---------------------------------------------------------------------------
// Action heads: softmax/sigmoid from raw h -> pc[p][s][8] =
// {rd0,rd1,rd2,wd0,wd1,wd2,rw0,rw1}. idx == p*2048 + s*8 + e.
// ---------------------------------------------------------------------------
__global__ __launch_bounds__(256) void head_kernel(
    const float* __restrict__ hout,  // [SEQ][32][16]
    float* __restrict__ pc) {        // [64][256][8]
  const int idx = blockIdx.x * 256 + threadIdx.x;
  const int e = idx & 7, s = (idx >> 3) & 255, p = idx >> 11;
  const int b = p >> 1, t = p & 1;
  const float* hp = hout + ((size_t)(s * 32 + b)) * 16 + t * 8;
  float outv;
  if (e < 3) {
    float a0 = hp[0], a1 = hp[1], a2 = hp[2];
    float m = fmaxf(a0, fmaxf(a1, a2));
    float e0 = __expf(a0 - m), e1 = __expf(a1 - m), e2 = __expf(a2 - m);
    float inv = 1.f / (e0 + e1 + e2);
    outv = (e == 0 ? e0 : (e == 1 ? e1 : e2)) * inv;
  } else if (e < 6) {
    float a3 = hp[3], a4 = hp[4], a5 = hp[5];
    float m = fmaxf(a3, fmaxf(a4, a5));
    float e0 = __expf(a3 - m), e1 = __expf(a4 - m), e2 = __expf(a5 - m);
    float inv = 1.f / (e0 + e1 + e2);
    outv = (e == 3 ? e0 : (e == 4 ? e1 : e2)) * inv;
  } else {
    outv = sigm(hp[e]);
  }
  pc[idx] = outv;
}

// ---------------------------------------------------------------------------
// Position precompute, 4x unrolled with 4-step coefficient prefetch from pc.
// ---------------------------------------------------------------------------
__global__ __launch_bounds__(64, 1) void pos_kernel(
    const float* __restrict__ pc,      // [64][256][8]
    float* __restrict__ posW, float* __restrict__ posRs,
    float* __restrict__ out_rpos, float* __restrict__ out_wpos) {
  const int p = blockIdx.x, lane = threadIdx.x;
  float r0 = 0, r1 = 0, r2 = 0, r3 = 0, w0 = 0, w1 = 0, w2 = 0, w3 = 0;
  if (lane == 0) { r0 = 1.f; w0 = 1.f; }
  const float* pcb = pc + (size_t)p * 2048;
  float4 c0 = *(const float4*)&pcb[0];
  float4 c1 = *(const float4*)&pcb[4];
  for (int s0 = 0; s0 < SEQ; s0 += 4) {
    float4 pf[8];
#pragma unroll
    for (int u = 0; u < 4; ++u) {
      int sn = s0 + u + 1; if (sn > 255) sn = 255;
      pf[2 * u]     = *(const float4*)&pcb[sn * 8];
      pf[2 * u + 1] = *(const float4*)&pcb[sn * 8 + 4];
    }
#pragma unroll
    for (int u = 0; u < 4; ++u) {
      const int s = s0 + u;
      size_t ob = ((size_t)p * 256 + s) * 256 + lane * 4;
      *(float4*)(posW + ob) = make_float4(w0, w1, w2, w3);
      float rw0 = c1.z;
      *(float4*)(posRs + ob) = make_float4(r0 * rw0, r1 * rw0, r2 * rw0, r3 * rw0);
      const float crd0 = c0.x, crd1 = c0.y, crd2 = c0.z;
      const float cwd0 = c0.w, cwd1 = c1.x, cwd2 = c1.y;
      float rn  = __shfl(r0, (lane + 1) & 63, 64);
      float rpv = __shfl(r3, (lane + 63) & 63, 64);
      float nw0 = r1 * cwd0 + w0 * cwd1 + rpv * cwd2;
      float nr0 = r1 * crd0 + r0 * crd1 + rpv * crd2;
      float nw1 = r2 * cwd0 + w1 * cwd1 + r0 * cwd2;
      float nr1 = r2 * crd0 + r1 * crd1 + r0 * crd2;
      float nw2 = r3 * cwd0 + w2 * cwd1 + r1 * cwd2;
      float nr2 = r3 * crd0 + r2 * crd1 + r1 * crd2;
      float nw3 = rn * cwd0 + w3 * cwd1 + r2 * cwd2;
      float nr3 = rn * crd0 + r3 * crd1 + r2 * crd2;
      r0 = nr0; r1 = nr1; r2 = nr2; r3 = nr3;
      w0 = nw0; w1 = nw1; w2 = nw2; w3 = nw3;
      c0 = pf[2 * u]; c1 = pf[2 * u + 1];
    }
  }
  out_rpos[(size_t)(lane * 4 + 0) * 64 + p] = r0;
  out_rpos[(size_t)(lane * 4 + 1) * 64 + p] = r1;
  out_rpos[(size_t)(lane * 4 + 2) * 64 + p] = r2;
  out_rpos[(size_t)(lane * 4 + 3) * 64 + p] = r3;
  out_wpos[(size_t)(lane * 4 + 0) * 64 + p] = w0;
  out_wpos[(size_t)(lane * 4 + 1) * 64 + p] = w1;
  out_wpos[(size_t)(lane * 4 + 2) * 64 + p] = w2;
  out_wpos[(size_t)(lane * 4 + 3) * 64 + p] = w3;
}

// ---------------------------------------------------------------------------
// Batched per-pair GEMM with hi/lo bf16 compensation (3 MFMA terms ~ f32).
// MODE: 0 plain, 1 strict-lower x rw1[row] (skips all-upper tiles),
//       2 lower-incl (zero-fills all-upper tiles without compute).
// ---------------------------------------------------------------------------
template<bool TRANS_A, bool B_NT, int MODE, int OUTK, int BROW>
__global__ __launch_bounds__(256) void bgemm(
    const float* __restrict__ A, const float* __restrict__ B,
    const float* __restrict__ pc, float* __restrict__ C,
    size_t sA, size_t sB) {
  __shared__ u16 Ah[128 * 40], Al[128 * 40], Bh[64 * 40], Bl[64 * 40];
  const int p = blockIdx.z;
  const int bm = blockIdx.y * 128, bn = blockIdx.x * 64;
  const int tid = threadIdx.x, wv = tid >> 6, lane = tid & 63;
  const int wm = wv >> 1, wn = wv & 1, l15 = lane & 15, l4 = lane >> 4;
  const int b = p >> 1, t = p & 1;

  if (MODE == 1 && bn >= bm + 128) return;
  if (MODE == 2 && bn >= bm + 128) {
#pragma unroll
    for (int mi = 0; mi < 4; ++mi)
#pragma unroll
      for (int ni = 0; ni < 2; ++ni)
#pragma unroll
        for (int r = 0; r < 4; ++r) {
          int row = bm + wm * 64 + mi * 16 + l4 * 4 + r;
          int col = bn + wn * 32 + ni * 16 + l15;
          C[(size_t)p * 65536 + (size_t)row * 256 + col] = 0.f;
        }
    return;
  }

  const float* Ap = A + (size_t)p * sA;
  const float* Bp = B + (size_t)p * sB;
  f32x4 acc[4][2] = {};

  for (int k0 = 0; k0 < 256; k0 += 32) {
    float xa[16];
    if (!TRANS_A) {
      const int m = tid >> 1, kq = (tid & 1) * 16;
      const float* src = Ap + (size_t)(bm + m) * 256 + k0 + kq;
#pragma unroll
      for (int j = 0; j < 4; ++j) *(float4*)(xa + j * 4) = ((const float4*)src)[j];
    } else {
      const int kr = tid >> 3, mq = (tid & 7) * 16;
      const float* src = Ap + (size_t)(k0 + kr) * 256 + bm + mq;
#pragma unroll
      for (int j = 0; j < 4; ++j) *(float4*)(xa + j * 4) = ((const float4*)src)[j];
    }
    u16 ah[16], al[16];
#pragma unroll
    for (int j = 0; j < 16; ++j) {
      u16 hh = f2bf(xa[j]);
      ah[j] = hh; al[j] = f2bf(xa[j] - bf2f(hh));
    }
    float xb[8];
    if (B_NT) {
      const int n = tid >> 2, kq = (tid & 3) * 8;
      const float* src = Bp + (size_t)(bn + n) * 256 + k0 + kq;
      *(float4*)(xb) = ((const float4*)src)[0];
      *(float4*)(xb + 4) = ((const float4*)src)[1];
    } else {
      const int kr = tid >> 3, nq = (tid & 7) * 8;
      const float* src = Bp + (size_t)(k0 + kr) * BROW + bn + nq;
      *(float4*)(xb) = ((const float4*)src)[0];
      *(float4*)(xb + 4) = ((const float4*)src)[1];
    }
    u16 bh[8], bl[8];
#pragma unroll
    for (int j = 0; j < 8; ++j) {
      u16 hh = f2bf(xb[j]);
      bh[j] = hh; bl[j] = f2bf(xb[j] - bf2f(hh));
    }
    __syncthreads();
    if (!TRANS_A) {
      const int m = tid >> 1, kq = (tid & 1) * 16;
      *(uint4*)&Ah[m * 40 + kq]     = *(const uint4*)(ah);
      *(uint4*)&Ah[m * 40 + kq + 8] = *(const uint4*)(ah + 8);
      *(uint4*)&Al[m * 40 + kq]     = *(const uint4*)(al);
      *(uint4*)&Al[m * 40 + kq + 8] = *(const uint4*)(al + 8);
    } else {
      const int kr = tid >> 3, mq = (tid & 7) * 16;
#pragma unroll
      for (int j = 0; j < 16; ++j) {
        Ah[(mq + j) * 40 + kr] = ah[j];
        Al[(mq + j) * 40 + kr] = al[j];
      }
    }
    if (B_NT) {
      const int n = tid >> 2, kq = (tid & 3) * 8;
      *(uint4*)&Bh[n * 40 + kq] = *(const uint4*)(bh);
      *(uint4*)&Bl[n * 40 + kq] = *(const uint4*)(bl);
    } else {
      const int kr = tid >> 3, nq = (tid & 7) * 8;
#pragma unroll
      for (int j = 0; j < 8; ++j) {
        Bh[(nq + j) * 40 + kr] = bh[j];
        Bl[(nq + j) * 40 + kr] = bl[j];
      }
    }
    __syncthreads();
    s16x8 fah[4], fal[4], fbh[2], fbl[2];
#pragma unroll
    for (int mi = 0; mi < 4; ++mi) {
      fah[mi] = *(const s16x8*)&Ah[(wm * 64 + mi * 16 + l15) * 40 + l4 * 8];
      fal[mi] = *(const s16x8*)&Al[(wm * 64 + mi * 16 + l15) * 40 + l4 * 8];
    }
#pragma unroll
    for (int ni = 0; ni < 2; ++ni) {
      fbh[ni] = *(const s16x8*)&Bh[(wn * 32 + ni * 16 + l15) * 40 + l4 * 8];
      fbl[ni] = *(const s16x8*)&Bl[(wn * 32 + ni * 16 + l15) * 40 + l4 * 8];
    }
#pragma unroll
    for (int mi = 0; mi < 4; ++mi)
#pragma unroll
      for (int ni = 0; ni < 2; ++ni) {
        acc[mi][ni] = __builtin_amdgcn_mfma_f32_16x16x32_bf16(fah[mi], fbh[ni], acc[mi][ni], 0, 0, 0);
        acc[mi][ni] = __builtin_amdgcn_mfma_f32_16x16x32_bf16(fah[mi], fbl[ni], acc[mi][ni], 0, 0, 0);
        acc[mi][ni] = __builtin_amdgcn_mfma_f32_16x16x32_bf16(fal[mi], fbh[ni], acc[mi][ni], 0, 0, 0);
      }
  }
#pragma unroll
  for (int mi = 0; mi < 4; ++mi)
#pragma unroll
    for (int ni = 0; ni < 2; ++ni)
#pragma unroll
      for (int r = 0; r < 4; ++r) {
        int row = bm + wm * 64 + mi * 16 + l4 * 4 + r;
        int col = bn + wn * 32 + ni * 16 + l15;
        float v = acc[mi][ni][r];
        if (MODE == 1) v = (col < row) ? v * pc[((size_t)p * 256 + row) * 8 + 7] : 0.f;
        if (MODE == 2) v = (col <= row) ? v : 0.f;
        if (OUTK == 0)      C[(size_t)p * 65536 + (size_t)row * 256 + col] = v;
        else if (OUTK == 1) C[((size_t)(row * 32 + b)) * 256 + t * 128 + col] = v;
        else                C[((size_t)row * 64 + p) * 128 + col] = v;
      }
}

// ---------------------------------------------------------------------------
// Blocked triangular solve (I + L) delta = rw1 * v.  Grid 128 = (pair, chalf).
// ---------------------------------------------------------------------------
__global__ __launch_bounds__(256) void solve_kernel(
    const float* __restrict__ L,        // [64][256][256] strict-lower, rw1-scaled
    const u16* __restrict__ values,     // bf16 [8192][256]
    const float* __restrict__ pc,       // [64][256][8]
    float* __restrict__ delta) {        // [64][256][128]
  const int p = blockIdx.x >> 1, half = blockIdx.x & 1;
  const int b = p >> 1, t = p & 1;
  const int tid = threadIdx.x, w = tid >> 6, lane = tid & 63;
  __shared__ float ds[256][64];
  __shared__ float Ps[32][64];
  __shared__ float Db[32][33];
  const float* Lp = L + (size_t)p * 65536;

  for (int k = 0; k < 8; ++k) {
    const int s0 = k * 32;
    float acc[8];
#pragma unroll
    for (int i = 0; i < 8; ++i) {
      const int s = s0 + w * 8 + i;
      float rv = bf2f(values[((size_t)(s * 32 + b)) * 256 + t * 128 + half * 64 + lane]);
      acc[i] = rv * pc[((size_t)p * 256 + s) * 8 + 7];
    }
    const float* Lr0 = Lp + (size_t)(s0 + w * 8) * 256;
#pragma unroll 4
    for (int j = 0; j < s0; ++j) {
      float dj = ds[j][lane];
#pragma unroll
      for (int i = 0; i < 8; ++i) acc[i] -= Lr0[(size_t)i * 256 + j] * dj;
    }
    {
      const int r = tid >> 3, q0 = (tid & 7) * 4;
      float4 dv = *(const float4*)(Lp + (size_t)(s0 + r) * 256 + s0 + q0);
      Db[r][q0] = dv.x; Db[r][q0 + 1] = dv.y; Db[r][q0 + 2] = dv.z; Db[r][q0 + 3] = dv.w;
    }
#pragma unroll
    for (int i = 0; i < 8; ++i) Ps[w * 8 + i][lane] = acc[i];
    __syncthreads();
    if (w == 0) {
      float d[32];
#pragma unroll
      for (int r = 0; r < 32; ++r) {
        float xa = Ps[r][lane], xb = 0.f;
#pragma unroll
        for (int q = 0; q < 32; ++q) {
          if (q < r) {
            if (q & 1) xb -= Db[r][q] * d[q];
            else       xa -= Db[r][q] * d[q];
          }
        }
        float x = xa + xb;
        d[r] = x;
        ds[s0 + r][lane] = x;
        delta[((size_t)p * 256 + s0 + r) * 128 + half * 64 + lane] = x;
      }
    }
    __syncthreads();
  }
}

// ---------------------------------------------------------------------------
extern "C" void kernel_launch(void* const* d_in, const int* in_sizes, int n_in,
                              void* d_out, int out_size, void* d_ws, size_t ws_size,
                              hipStream_t stream) {
  const float* inputs = (const float*)d_in[0];
  const float* W_ih = (const float*)d_in[2];
  const float* W_hh = (const float*)d_in[3];
  const float* b_ih = (const float*)d_in[4];
  const float* b_hh = (const float*)d_in[5];
  const float* W_val = (const float*)d_in[6];
  const float* b_val = (const float*)d_in[7];
  const float* W_out = (const float*)d_in[8];
  const float* b_out = (const float*)d_in[9];

  float* out = (float*)d_out;
  float* out_tape = out + 2097152;
  float* out_rpos = out + 4194304;
  float* out_wpos = out + 4210688;

  char* ws = (char*)d_ws;
  float* posW      = (float*)(ws);                    // 16 MB  [64][256][256]
  float* posRs     = (float*)(ws + 16777216);         // 16 MB  (reused: reads_f32)
  float* LHm       = (float*)(ws + 33554432);         // 16 MB  (L, then Hm)
  u16*   values_bf = (u16*)  (ws + 50331648);         //  4 MB
  float* xg        = (float*)(ws + 54525952);         //  2 MB (dead after lstm)
  float* delta     = (float*)(ws + 54525952);         //  8 MB (aliases xg)
  float* pcb       = (float*)(ws + 62914560);         // 512 KB [64][256][8]
  float* hout      = (float*)(ws + 63438848);         // 512 KB [256][32][16]
  float* reads_f32 = posRs;

  // 1. values (bf16) = inputs @ W_val^T + b_val
  gemm_mfma<false, true><<<dim3(64, 4), 256, 0, stream>>>(inputs, W_val, b_val, values_bf, 256);
  // 2. xg (f32) = inputs @ W_ih^T + (b_ih + b_hh)
  gemm_nt<<<dim3(128, 1), 256, 0, stream>>>(inputs, W_ih, b_ih, b_hh, xg, 64);
  // 3. LSTM core -> raw h
  lstm_kernel<<<32, 64, 0, stream>>>(xg, W_hh, hout);
  // 3b. action heads -> packed coefficients pc
  head_kernel<<<512, 256, 0, stream>>>(hout, pcb);
  // 4. position trajectories
  pos_kernel<<<64, 64, 0, stream>>>(pcb, posW, posRs, out_rpos, out_wpos);
  // 5. L = rw1 (.) strict_tril(posW posW^T)
  bgemm<false, true, 1, 0, 256><<<dim3(4, 2, 64), 256, 0, stream>>>(
      posW, posW, pcb, LHm, 65536, 65536);
  // 6. blocked triangular solve -> delta
  solve_kernel<<<128, 256, 0, stream>>>(LHm, values_bf, pcb, delta);
  // 7. Hm = tril_incl(posRs posW^T)   (overwrites L)
  bgemm<false, true, 2, 0, 256><<<dim3(4, 2, 64), 256, 0, stream>>>(
      posRs, posW, pcb, LHm, 65536, 65536);
  // 8. reads = Hm @ delta   (reads layout [s*32+b][256])
  bgemm<false, false, 0, 1, 128><<<dim3(2, 2, 64), 256, 0, stream>>>(
      LHm, delta, pcb, reads_f32, 65536, 32768);
  // 9. out_tape = posW^T @ delta
  bgemm<true, false, 0, 2, 128><<<dim3(2, 2, 64), 256, 0, stream>>>(
      posW, delta, pcb, out_tape, 65536, 32768);
  // 10. outputs = reads @ W_out^T + b_out
  gemm_mfma<false, false><<<dim3(64, 4), 256, 0, stream>>>(reads_f32, W_out, b_out, out, 256);
}